// Round 1
// baseline (1250.483 us; speedup 1.0000x reference)
//
#include <hip/hip_runtime.h>
#include <hip/hip_bf16.h>
#include <cstdint>
#include <math.h>

// Problem dims (fixed)
#define BB 2
#define TT 2048
#define DD 4096
#define HQ 32
#define HKV 8
#define DK 128
#define MM (BB*TT)          // 4096 rows
#define NQ (HQ*DK)          // 4096
#define NKV (HKV*DK)        // 1024

typedef __attribute__((ext_vector_type(8))) short short8;
typedef __attribute__((ext_vector_type(4))) short bshort4;
typedef __attribute__((ext_vector_type(4))) float floatx4;

typedef unsigned int u32;
typedef __attribute__((address_space(1))) const u32 gas_u32;
typedef __attribute__((address_space(3))) u32 las_u32;

// async global->LDS, 16B per lane. LDS dest must be wave-uniform base + lane*16
// (our tid-linear chunk mapping satisfies this).
__device__ __forceinline__ void gl_lds16(const uint16_t* g, uint16_t* l) {
    __builtin_amdgcn_global_load_lds((gas_u32*)g, (las_u32*)l, 16, 0, 0);
}

__device__ inline uint16_t f2bf(float f) {
    uint32_t u = __float_as_uint(f);
    uint32_t r = (u + 0x7fffu + ((u >> 16) & 1u)) >> 16;
    return (uint16_t)r;
}

// ---------------- RoPE tables: cos/sin [2048][64] ----------------
__global__ void rope_tables_k(float* __restrict__ cosT, float* __restrict__ sinT) {
    int t = blockIdx.x;        // 0..2047
    int d = threadIdx.x;       // 0..63
    float theta = expf(-(float)d * (9.210340371976184f / 64.0f));
    float arg = (float)t * theta;
    float s, c;
    sincosf(arg, &s, &c);
    cosT[t * 64 + d] = c;
    sinT[t * 64 + d] = s;
}

// ------------- transpose-convert weights: W (K x N fp32) -> WT (N x K bf16) -------------
__global__ void wconv_k(const float* __restrict__ W, uint16_t* __restrict__ WT, int K, int N) {
    __shared__ float tile[32][33];
    int n0 = blockIdx.x * 32, k0 = blockIdx.y * 32;
    int tx = threadIdx.x, ty = threadIdx.y;  // (32, 8)
#pragma unroll
    for (int i = 0; i < 4; i++) {
        int r = k0 + ty + i * 8;
        tile[ty + i * 8][tx] = W[(size_t)r * N + n0 + tx];
    }
    __syncthreads();
#pragma unroll
    for (int i = 0; i < 4; i++) {
        int r = n0 + ty + i * 8;
        WT[(size_t)r * K + k0 + tx] = f2bf(tile[tx][ty + i * 8]);
    }
}

// ------------- activation convert fp32 -> bf16 (flat) -------------
__global__ void aconv_k(const float4* __restrict__ X, uint2* __restrict__ Y, int n4) {
    int i = blockIdx.x * blockDim.x + threadIdx.x;
    if (i < n4) {
        float4 v = X[i];
        uint2 o;
        o.x = (uint32_t)f2bf(v.x) | ((uint32_t)f2bf(v.y) << 16);
        o.y = (uint32_t)f2bf(v.z) | ((uint32_t)f2bf(v.w) << 16);
        Y[i] = o;
    }
}

// ------------- GEMM: C = A(MxK,bf16,K-major) * B(NxK,bf16,K-major)^T -------------
// m97 structure: global_load_lds width-16 staging into linear (unpadded) LDS,
// 2 barriers per K-step, 128x128 tile, 4 waves, 16x16x32 MFMA.
// EPI: 1=Q(rope->bf16), 2=K(rope->bf16 + fp32 cache), 3=V(bf16 + fp32 cache), 4=fp32 out
template <int EPI>
__global__ __launch_bounds__(256) void gemm_k(
    const uint16_t* __restrict__ A, const uint16_t* __restrict__ Bm,
    int M, int N, int K,
    uint16_t* __restrict__ Obf, float* __restrict__ Ofp,
    const float* __restrict__ cosT, const float* __restrict__ sinT)
{
    __shared__ __attribute__((aligned(16))) uint16_t As[128 * 64];
    __shared__ __attribute__((aligned(16))) uint16_t Bs[128 * 64];
    int m0 = blockIdx.y * 128;
    int n0 = blockIdx.x * 128;
    int tid = threadIdx.x;
    int lane = tid & 63, wave = tid >> 6;
    int l15 = lane & 15, quad = lane >> 4;

    floatx4 acc[2][8];
#pragma unroll
    for (int a = 0; a < 2; a++)
#pragma unroll
        for (int b = 0; b < 8; b++) acc[a][b] = floatx4{0.f, 0.f, 0.f, 0.f};

    // staging mapping: chunk = tid + i*256; row = chunk>>3 (128B/row), kc = chunk&7
    int srow = tid >> 3, skc = tid & 7;
    const uint16_t* Ag = A + (size_t)(m0 + srow) * K + skc * 8;
    const uint16_t* Bg = Bm + (size_t)(n0 + srow) * K + skc * 8;
    uint16_t* Asl = As + tid * 8;   // chunk*16B, linear in tid per wave
    uint16_t* Bsl = Bs + tid * 8;

    for (int k0 = 0; k0 < K; k0 += 64) {
        __syncthreads();             // previous tile's readers done
#pragma unroll
        for (int i = 0; i < 4; i++) {
            gl_lds16(Ag + (size_t)(i * 32) * K + k0, Asl + i * 2048);
            gl_lds16(Bg + (size_t)(i * 32) * K + k0, Bsl + i * 2048);
        }
        __syncthreads();             // compiler drains vmcnt(0) before barrier
#pragma unroll
        for (int ks = 0; ks < 2; ks++) {
            short8 af[2], bfr[8];
#pragma unroll
            for (int mt = 0; mt < 2; mt++)
                af[mt] = *(const short8*)(As + (wave * 32 + mt * 16 + l15) * 64 + ks * 32 + quad * 8);
#pragma unroll
            for (int nt = 0; nt < 8; nt++)
                bfr[nt] = *(const short8*)(Bs + (nt * 16 + l15) * 64 + ks * 32 + quad * 8);
#pragma unroll
            for (int mt = 0; mt < 2; mt++)
#pragma unroll
                for (int nt = 0; nt < 8; nt++)
                    acc[mt][nt] = __builtin_amdgcn_mfma_f32_16x16x32_bf16(af[mt], bfr[nt], acc[mt][nt], 0, 0, 0);
        }
    }

    // Epilogue. C layout: row = quad*4+reg (+ wave*32 + mt*16), col = l15 + nt*16.
#pragma unroll
    for (int mt = 0; mt < 2; mt++) {
        int rbase = m0 + wave * 32 + mt * 16 + quad * 4;
        if (EPI == 4) {
#pragma unroll
            for (int nt = 0; nt < 8; nt++) {
                int c = n0 + nt * 16 + l15;
#pragma unroll
                for (int r = 0; r < 4; r++)
                    Ofp[(size_t)(rbase + r) * N + c] = acc[mt][nt][r];
            }
        } else if (EPI == 3) {  // V: bf16 vh + fp32 cache[...,128+d]
            int h = n0 >> 7;
#pragma unroll
            for (int nt = 0; nt < 8; nt++) {
                int cb = nt * 16 + l15;  // d in 0..127
#pragma unroll
                for (int r = 0; r < 4; r++) {
                    int row = rbase + r;
                    float v = acc[mt][nt][r];
                    Obf[(size_t)row * N + n0 + cb] = f2bf(v);
                    Ofp[((size_t)row * 8 + h) * 256 + 128 + cb] = v;
                }
            }
        } else {  // Q / K with RoPE: pairs (cb, cb+64) share theta index cb
            int h = n0 >> 7;
#pragma unroll
            for (int nt = 0; nt < 4; nt++) {
                int cb = nt * 16 + l15;  // 0..63
#pragma unroll
                for (int r = 0; r < 4; r++) {
                    int row = rbase + r;
                    int t = row & (TT - 1);
                    float cs = cosT[t * 64 + cb];
                    float sn = sinT[t * 64 + cb];
                    float x1 = acc[mt][nt][r], x2 = acc[mt][nt + 4][r];
                    float o1 = x1 * cs - x2 * sn;
                    float o2 = x2 * cs + x1 * sn;
                    Obf[(size_t)row * N + n0 + cb] = f2bf(o1);
                    Obf[(size_t)row * N + n0 + cb + 64] = f2bf(o2);
                    if (EPI == 2) {
                        Ofp[((size_t)row * 8 + h) * 256 + cb] = o1;
                        Ofp[((size_t)row * 8 + h) * 256 + cb + 64] = o2;
                    }
                }
            }
        }
    }
}

// ------------- transpose v_heads: vh[b*2048+t][h*128+d] -> vT[(b*8+h)*128+d][t] -------------
__global__ void vtrans_k(const uint16_t* __restrict__ vh, uint16_t* __restrict__ vT) {
    __shared__ uint16_t tile[32][33];
    int bh = blockIdx.z;           // b*8+h
    int t0 = blockIdx.x * 32;
    int d0 = blockIdx.y * 32;
    int b = bh >> 3, h = bh & 7;
    int tx = threadIdx.x, ty = threadIdx.y;
#pragma unroll
    for (int i = 0; i < 4; i++) {
        int t = t0 + ty + i * 8;
        tile[ty + i * 8][tx] = vh[(size_t)(b * TT + t) * NKV + h * DK + d0 + tx];
    }
    __syncthreads();
#pragma unroll
    for (int i = 0; i < 4; i++) {
        int d = d0 + ty + i * 8;
        vT[((size_t)bh * DK + d) * TT + t0 + tx] = tile[tx][ty + i * 8];
    }
}

// ------------- flash attention v2 -------------
// Block = 4 waves = the 4 Q heads of one KV group. Each wave: 32 Q rows (2 col-tiles).
// K tile (32x128) and V^T tile (128x32) staged in LDS, shared by all 4 waves.
// S^T computed via swapped MFMA operands (A=K rows=keys, B=Q cols=qrows) so softmax
// state is per-lane (l15 = qrow); reductions are 2 shfl_xor over the quad dim.
// Causal balancing: block x processes Q-tile pair (x, 63-x) -> 65 key-tiles/block.
// T13 defer-max: skip the O-rescale (and m update) when no row's tile-max exceeds
// the running max by >8 (log2 domain; P bounded by 2^8, fine in bf16).
__global__ __launch_bounds__(256) void attn_k(
    const uint16_t* __restrict__ qh, const uint16_t* __restrict__ kh,
    const uint16_t* __restrict__ vT, uint16_t* __restrict__ ob)
{
    __shared__ __attribute__((aligned(16))) uint16_t Ks[32 * 136];   // [key][d], pad 8
    __shared__ __attribute__((aligned(16))) uint16_t Vs[128 * 40];   // [dv][key], pad 8
    __shared__ __attribute__((aligned(16))) uint16_t Ps[4 * 32 * 40];// per-wave P [qrow][key]

    int tid = threadIdx.x;
    int lane = tid & 63, wave = tid >> 6;
    int l15 = lane & 15, quad = lane >> 4;
    int kvh = blockIdx.y;
    int b = blockIdx.z;
    int hq = wave * 8 + kvh;            // G*8+H mapping: Q heads of group = {kvh, kvh+8, +16, +24}
    uint16_t* P = Ps + wave * (32 * 40);

    const uint16_t* kbase = kh + (size_t)(b * TT) * NKV + kvh * DK;
    const uint16_t* vbase = vT + ((size_t)(b * 8 + kvh) * DK) * TT;
    const float scale2 = 0.08838834764831845f * 1.4426950408889634f;  // 1/sqrt(128) * log2(e)

    int kkey = tid >> 4, kdc = tid & 15;   // K staging: 16 keys/round x 16B chunks
    int vdv = tid >> 2, vtc = tid & 3;     // V staging: 64 dv/round x 16B chunks of keys

    for (int half = 0; half < 2; half++) {
        int hh = half ? (63 - (int)blockIdx.x) : (int)blockIdx.x;
        int q0 = hh * 32;
        int ntiles = hh + 1;

        // Q B-frags (x32 B-layout: lane l15 = qrow, k = ks*32 + quad*8 + j)
        short8 qf[2][4];
#pragma unroll
        for (int qc = 0; qc < 2; qc++) {
            const uint16_t* qr = qh + (size_t)(b * TT + q0 + qc * 16 + l15) * NQ + hq * DK;
#pragma unroll
            for (int ks = 0; ks < 4; ks++)
                qf[qc][ks] = *(const short8*)(qr + ks * 32 + quad * 8);
        }

        floatx4 O[2][8];
#pragma unroll
        for (int qc = 0; qc < 2; qc++)
#pragma unroll
            for (int vt = 0; vt < 8; vt++) O[qc][vt] = floatx4{0.f, 0.f, 0.f, 0.f};
        float m_[2] = {-INFINITY, -INFINITY};
        float l_[2] = {0.f, 0.f};

        // prefetch tile 0 into regs
        short8 kst[2], vst[2];
#pragma unroll
        for (int i = 0; i < 2; i++) {
            kst[i] = *(const short8*)(kbase + (size_t)(kkey + i * 16) * NKV + kdc * 8);
            vst[i] = *(const short8*)(vbase + (size_t)(vdv + i * 64) * TT + vtc * 8);
        }

        for (int t = 0; t < ntiles; t++) {
            int kb0 = t * 32;
            __syncthreads();   // previous tile's LDS readers done
#pragma unroll
            for (int i = 0; i < 2; i++) {
                *(short8*)(Ks + (kkey + i * 16) * 136 + kdc * 8) = kst[i];
                *(short8*)(Vs + (vdv + i * 64) * 40 + vtc * 8) = vst[i];
            }
            __syncthreads();
            if (t + 1 < ntiles) {   // prefetch next tile (overlaps compute below)
                int kn = kb0 + 32;
#pragma unroll
                for (int i = 0; i < 2; i++) {
                    kst[i] = *(const short8*)(kbase + (size_t)(kn + kkey + i * 16) * NKV + kdc * 8);
                    vst[i] = *(const short8*)(vbase + (size_t)(vdv + i * 64) * TT + kn + vtc * 8);
                }
            }
            // ---- S^T = K * Q^T : C rows = keys (quad*4+r), cols = qrows (l15) ----
            floatx4 s[2][2];
            s[0][0] = floatx4{0.f,0.f,0.f,0.f}; s[0][1] = floatx4{0.f,0.f,0.f,0.f};
            s[1][0] = floatx4{0.f,0.f,0.f,0.f}; s[1][1] = floatx4{0.f,0.f,0.f,0.f};
#pragma unroll
            for (int ks = 0; ks < 4; ks++) {
                short8 kf0 = *(const short8*)(Ks + l15 * 136 + ks * 32 + quad * 8);
                short8 kf1 = *(const short8*)(Ks + (16 + l15) * 136 + ks * 32 + quad * 8);
                s[0][0] = __builtin_amdgcn_mfma_f32_16x16x32_bf16(kf0, qf[0][ks], s[0][0], 0, 0, 0);
                s[0][1] = __builtin_amdgcn_mfma_f32_16x16x32_bf16(kf0, qf[1][ks], s[0][1], 0, 0, 0);
                s[1][0] = __builtin_amdgcn_mfma_f32_16x16x32_bf16(kf1, qf[0][ks], s[1][0], 0, 0, 0);
                s[1][1] = __builtin_amdgcn_mfma_f32_16x16x32_bf16(kf1, qf[1][ks], s[1][1], 0, 0, 0);
            }
            bool maskT = (t == ntiles - 1);   // only the diagonal tile needs masking
#pragma unroll
            for (int qc = 0; qc < 2; qc++) {
                int qrow = q0 + qc * 16 + l15;
                float p[8];
#pragma unroll
                for (int krt = 0; krt < 2; krt++)
#pragma unroll
                    for (int r = 0; r < 4; r++) {
                        float v = s[krt][qc][r] * scale2;
                        if (maskT && (kb0 + krt * 16 + quad * 4 + r > qrow)) v = -INFINITY;
                        p[krt * 4 + r] = v;
                    }
                float mx = p[0];
#pragma unroll
                for (int j = 1; j < 8; j++) mx = fmaxf(mx, p[j]);
                mx = fmaxf(mx, __shfl_xor(mx, 16));
                mx = fmaxf(mx, __shfl_xor(mx, 32));
                // T13 defer-max: wave-uniform skip of the rescale pass
                bool noresc = (bool)__all(mx <= m_[qc] + 8.0f);
                float mnew = noresc ? m_[qc] : fmaxf(m_[qc], mx);
                float e[8], sum = 0.f;
#pragma unroll
                for (int j = 0; j < 8; j++) { e[j] = exp2f(p[j] - mnew); sum += e[j]; }
                sum += __shfl_xor(sum, 16);
                sum += __shfl_xor(sum, 32);
                if (noresc) {
                    l_[qc] += sum;
                } else {
                    float al = exp2f(m_[qc] - mnew);
                    l_[qc] = l_[qc] * al + sum;
                    m_[qc] = mnew;
                    // broadcast alpha from lane l15=quad*4+r for O (row-indexed) rescale
                    float ar[4];
#pragma unroll
                    for (int r = 0; r < 4; r++) ar[r] = __shfl(al, quad * 4 + r);
#pragma unroll
                    for (int vt = 0; vt < 8; vt++)
#pragma unroll
                        for (int r = 0; r < 4; r++) O[qc][vt][r] *= ar[r];
                }
                // pack P^T -> LDS as P[qrow][key] (bf16, round-to-nearest)
                bshort4 pw0, pw1;
#pragma unroll
                for (int r = 0; r < 4; r++) {
                    pw0[r] = (short)((__float_as_uint(e[r]) + 0x8000u) >> 16);
                    pw1[r] = (short)((__float_as_uint(e[4 + r]) + 0x8000u) >> 16);
                }
                *(bshort4*)(P + (qc * 16 + l15) * 40 + quad * 4) = pw0;
                *(bshort4*)(P + (qc * 16 + l15) * 40 + 16 + quad * 4) = pw1;
            }
            // ---- O += P * V^T : A = P (m=qrow), B = V^T (n=dv) ----
            short8 pf0 = *(const short8*)(P + l15 * 40 + quad * 8);
            short8 pf1 = *(const short8*)(P + (16 + l15) * 40 + quad * 8);
#pragma unroll
            for (int vt = 0; vt < 8; vt++) {
                short8 vf = *(const short8*)(Vs + (vt * 16 + l15) * 40 + quad * 8);
                O[0][vt] = __builtin_amdgcn_mfma_f32_16x16x32_bf16(pf0, vf, O[0][vt], 0, 0, 0);
                O[1][vt] = __builtin_amdgcn_mfma_f32_16x16x32_bf16(pf1, vf, O[1][vt], 0, 0, 0);
            }
        }
        // epilogue: O C-layout row = qrow (quad*4+r), col = dv (vt*16+l15)
#pragma unroll
        for (int qc = 0; qc < 2; qc++) {
            float lr[4];
#pragma unroll
            for (int r = 0; r < 4; r++) lr[r] = 1.0f / __shfl(l_[qc], quad * 4 + r);
#pragma unroll
            for (int r = 0; r < 4; r++) {
                size_t row = (size_t)(b * TT + q0 + qc * 16 + quad * 4 + r);
#pragma unroll
                for (int vt = 0; vt < 8; vt++)
                    ob[row * NQ + hq * DK + vt * 16 + l15] = f2bf(O[qc][vt][r] * lr[r]);
            }
        }
    }
}

extern "C" void kernel_launch(void* const* d_in, const int* in_sizes, int n_in,
                              void* d_out, int out_size, void* d_ws, size_t ws_size,
                              hipStream_t stream)
{
    const float* q  = (const float*)d_in[0];
    const float* k  = (const float*)d_in[1];
    const float* v  = (const float*)d_in[2];
    const float* wq = (const float*)d_in[3];
    const float* wk = (const float*)d_in[4];
    const float* wv = (const float*)d_in[5];
    const float* wo = (const float*)d_in[6];
    float* out   = (float*)d_out;                       // [2,2048,4096]
    float* cache = out + (size_t)MM * DD;               // [2,2048,8,256]

    char* ws = (char*)d_ws;
    float* cosT = (float*)ws;
    float* sinT = cosT + TT * 64;
    size_t off = 1u << 20;  // 1 MB
    const size_t SZ32 = (size_t)MM * DD * 2;   // 32 MB (bf16 4096x4096)
    const size_t SZ8  = (size_t)MM * NKV * 2;  // 8 MB  (bf16 4096x1024)
    uint16_t* wqT = (uint16_t*)(ws + off); off += SZ32;   // 4096x4096
    uint16_t* wkT = (uint16_t*)(ws + off); off += SZ8;    // 1024x4096
    uint16_t* wvT = (uint16_t*)(ws + off); off += SZ8;    // 1024x4096
    uint16_t* qb  = (uint16_t*)(ws + off); off += SZ32;
    uint16_t* kb  = (uint16_t*)(ws + off); off += SZ32;
    uint16_t* vb  = (uint16_t*)(ws + off); off += SZ32;
    uint16_t* khB = (uint16_t*)(ws + off); off += SZ8;
    uint16_t* vhB = (uint16_t*)(ws + off); off += SZ8;
    // aliases (stream-ordered reuse):
    uint16_t* vTr = wvT;  // after V GEMM done with wvT
    uint16_t* qhB = vb;   // after V GEMM done with vb
    uint16_t* woT = kb;   // after K GEMM done with kb
    uint16_t* obf = qb;   // after Q GEMM done with qb

    // 1. RoPE tables
    rope_tables_k<<<TT, 64, 0, stream>>>(cosT, sinT);
    // 2. weight convert/transpose (wq, wk, wv)
    wconv_k<<<dim3(NQ / 32, DD / 32), dim3(32, 8), 0, stream>>>(wq, wqT, DD, NQ);
    wconv_k<<<dim3(NKV / 32, DD / 32), dim3(32, 8), 0, stream>>>(wk, wkT, DD, NKV);
    wconv_k<<<dim3(NKV / 32, DD / 32), dim3(32, 8), 0, stream>>>(wv, wvT, DD, NKV);
    // 3. activation converts
    int n4 = MM * DD / 4;
    aconv_k<<<(n4 + 255) / 256, 256, 0, stream>>>((const float4*)q, (uint2*)qb, n4);
    aconv_k<<<(n4 + 255) / 256, 256, 0, stream>>>((const float4*)k, (uint2*)kb, n4);
    aconv_k<<<(n4 + 255) / 256, 256, 0, stream>>>((const float4*)v, (uint2*)vb, n4);
    // 4. V GEMM (writes vh bf16 + cache fp32)
    gemm_k<3><<<dim3(NKV / 128, MM / 128), 256, 0, stream>>>(vb, wvT, MM, NKV, DD, vhB, cache, cosT, sinT);
    // 5. K GEMM (RoPE; writes kh bf16 + cache fp32)
    gemm_k<2><<<dim3(NKV / 128, MM / 128), 256, 0, stream>>>(kb, wkT, MM, NKV, DD, khB, cache, cosT, sinT);
    // 6. Q GEMM (RoPE; writes qh bf16 into vb's space)
    gemm_k<1><<<dim3(NQ / 128, MM / 128), 256, 0, stream>>>(qb, wqT, MM, NQ, DD, qhB, nullptr, cosT, sinT);
    // 7. wo convert (into kb's space)
    wconv_k<<<dim3(DD / 32, DD / 32), dim3(32, 8), 0, stream>>>(wo, woT, DD, DD);
    // 8. V transpose (into wvT's space)
    vtrans_k<<<dim3(TT / 32, DK / 32, BB * HKV), dim3(32, 8), 0, stream>>>(vhB, vTr);
    // 9. attention (into qb's space): grid = (qtile pairs, kv heads, batch)
    attn_k<<<dim3(32, HKV, BB), 256, 0, stream>>>(qhB, khB, vTr, obf);
    // 10. output projection -> fp32 out
    gemm_k<4><<<dim3(DD / 128, MM / 128), 256, 0, stream>>>(obf, woT, MM, DD, DD, nullptr, out, cosT, sinT);
}

// Round 2
// 1140.446 us; speedup vs baseline: 1.0965x; 1.0965x over previous
//
#include <hip/hip_runtime.h>
#include <hip/hip_bf16.h>
#include <cstdint>
#include <math.h>

// Problem dims (fixed)
#define BB 2
#define TT 2048
#define DD 4096
#define HQ 32
#define HKV 8
#define DK 128
#define MM (BB*TT)          // 4096 rows
#define NQ (HQ*DK)          // 4096
#define NKV (HKV*DK)        // 1024

typedef __attribute__((ext_vector_type(8))) short short8;
typedef __attribute__((ext_vector_type(4))) short bshort4;
typedef __attribute__((ext_vector_type(4))) float floatx4;

typedef unsigned int u32;
typedef __attribute__((address_space(1))) const u32 gas_u32;
typedef __attribute__((address_space(3))) u32 las_u32;

// async global->LDS, 16B per lane. LDS dest must be wave-uniform base + lane*16
// (our tid-linear chunk mapping satisfies this).
__device__ __forceinline__ void gl_lds16(const uint16_t* g, uint16_t* l) {
    __builtin_amdgcn_global_load_lds((gas_u32*)g, (las_u32*)l, 16, 0, 0);
}

__device__ inline uint16_t f2bf(float f) {
    uint32_t u = __float_as_uint(f);
    uint32_t r = (u + 0x7fffu + ((u >> 16) & 1u)) >> 16;
    return (uint16_t)r;
}

// ---------------- RoPE tables: cos/sin [2048][64] ----------------
__global__ void rope_tables_k(float* __restrict__ cosT, float* __restrict__ sinT) {
    int t = blockIdx.x;        // 0..2047
    int d = threadIdx.x;       // 0..63
    float theta = expf(-(float)d * (9.210340371976184f / 64.0f));
    float arg = (float)t * theta;
    float s, c;
    sincosf(arg, &s, &c);
    cosT[t * 64 + d] = c;
    sinT[t * 64 + d] = s;
}

// ------------- transpose-convert weights: W (K x N fp32) -> WT (N x K bf16) -------------
__global__ void wconv_k(const float* __restrict__ W, uint16_t* __restrict__ WT, int K, int N) {
    __shared__ float tile[32][33];
    int n0 = blockIdx.x * 32, k0 = blockIdx.y * 32;
    int tx = threadIdx.x, ty = threadIdx.y;  // (32, 8)
#pragma unroll
    for (int i = 0; i < 4; i++) {
        int r = k0 + ty + i * 8;
        tile[ty + i * 8][tx] = W[(size_t)r * N + n0 + tx];
    }
    __syncthreads();
#pragma unroll
    for (int i = 0; i < 4; i++) {
        int r = n0 + ty + i * 8;
        WT[(size_t)r * K + k0 + tx] = f2bf(tile[tx][ty + i * 8]);
    }
}

// ------------- activation convert fp32 -> bf16 (flat) -------------
__global__ void aconv_k(const float4* __restrict__ X, uint2* __restrict__ Y, int n4) {
    int i = blockIdx.x * blockDim.x + threadIdx.x;
    if (i < n4) {
        float4 v = X[i];
        uint2 o;
        o.x = (uint32_t)f2bf(v.x) | ((uint32_t)f2bf(v.y) << 16);
        o.y = (uint32_t)f2bf(v.z) | ((uint32_t)f2bf(v.w) << 16);
        Y[i] = o;
    }
}

// ------------- GEMM: C = A(MxK,bf16,K-major) * B(NxK,bf16,K-major)^T -------------
// m97 structure: global_load_lds width-16 staging into linear LDS, 2 barriers per
// K-step, 128x128 tile, 4 waves, 16x16x32 MFMA.
// T2 swizzle (rule #21, both-sides): LDS chunk position c of row r holds global
// chunk c^(r&7). Source is pre-swizzled (skc), read XORs the same pattern ->
// conflict-free ds_read_b128 (each 8-lane group covers all 8 16B bank-groups).
// EPI: 1=Q(rope->bf16), 2=K(rope->bf16 + fp32 cache), 3=V(bf16 + fp32 cache), 4=fp32 out
template <int EPI>
__global__ __launch_bounds__(256) void gemm_k(
    const uint16_t* __restrict__ A, const uint16_t* __restrict__ Bm,
    int M, int N, int K,
    uint16_t* __restrict__ Obf, float* __restrict__ Ofp,
    const float* __restrict__ cosT, const float* __restrict__ sinT)
{
    __shared__ __attribute__((aligned(16))) uint16_t As[128 * 64];
    __shared__ __attribute__((aligned(16))) uint16_t Bs[128 * 64];
    int m0 = blockIdx.y * 128;
    int n0 = blockIdx.x * 128;
    int tid = threadIdx.x;
    int lane = tid & 63, wave = tid >> 6;
    int l15 = lane & 15, quad = lane >> 4;

    floatx4 acc[2][8];
#pragma unroll
    for (int a = 0; a < 2; a++)
#pragma unroll
        for (int b = 0; b < 8; b++) acc[a][b] = floatx4{0.f, 0.f, 0.f, 0.f};

    // staging mapping: chunk = tid + i*256; row = chunk>>3 (128B/row), pos = chunk&7.
    // LDS pos holds global chunk pos^(row&7); row&7 = (tid>>3)&7 (i*32 == 0 mod 8).
    int srow = tid >> 3;
    int skc = (tid & 7) ^ (srow & 7);          // pre-swizzled global chunk index
    const uint16_t* Ag = A + (size_t)(m0 + srow) * K + skc * 8;
    const uint16_t* Bg = Bm + (size_t)(n0 + srow) * K + skc * 8;
    uint16_t* Asl = As + tid * 8;   // linear dest: chunk*16B
    uint16_t* Bsl = Bs + tid * 8;

    int rswA = l15 & 7;             // read-side XOR (row&7 for fragment rows)

    for (int k0 = 0; k0 < K; k0 += 64) {
        __syncthreads();             // previous tile's readers done
#pragma unroll
        for (int i = 0; i < 4; i++) {
            gl_lds16(Ag + (size_t)(i * 32) * K + k0, Asl + i * 2048);
            gl_lds16(Bg + (size_t)(i * 32) * K + k0, Bsl + i * 2048);
        }
        __syncthreads();             // compiler drains vmcnt(0) before barrier
#pragma unroll
        for (int ks = 0; ks < 2; ks++) {
            short8 af[2], bfr[8];
#pragma unroll
            for (int mt = 0; mt < 2; mt++)
                af[mt] = *(const short8*)(As + (wave * 32 + mt * 16 + l15) * 64
                                             + (((ks << 2) | quad) ^ rswA) * 8);
#pragma unroll
            for (int nt = 0; nt < 8; nt++)
                bfr[nt] = *(const short8*)(Bs + (nt * 16 + l15) * 64
                                              + (((ks << 2) | quad) ^ rswA) * 8);
#pragma unroll
            for (int mt = 0; mt < 2; mt++)
#pragma unroll
                for (int nt = 0; nt < 8; nt++)
                    acc[mt][nt] = __builtin_amdgcn_mfma_f32_16x16x32_bf16(af[mt], bfr[nt], acc[mt][nt], 0, 0, 0);
        }
    }

    // Epilogue. C layout: row = quad*4+reg (+ wave*32 + mt*16), col = l15 + nt*16.
#pragma unroll
    for (int mt = 0; mt < 2; mt++) {
        int rbase = m0 + wave * 32 + mt * 16 + quad * 4;
        if (EPI == 4) {
#pragma unroll
            for (int nt = 0; nt < 8; nt++) {
                int c = n0 + nt * 16 + l15;
#pragma unroll
                for (int r = 0; r < 4; r++)
                    Ofp[(size_t)(rbase + r) * N + c] = acc[mt][nt][r];
            }
        } else if (EPI == 3) {  // V: bf16 vh + fp32 cache[...,128+d]
            int h = n0 >> 7;
#pragma unroll
            for (int nt = 0; nt < 8; nt++) {
                int cb = nt * 16 + l15;  // d in 0..127
#pragma unroll
                for (int r = 0; r < 4; r++) {
                    int row = rbase + r;
                    float v = acc[mt][nt][r];
                    Obf[(size_t)row * N + n0 + cb] = f2bf(v);
                    Ofp[((size_t)row * 8 + h) * 256 + 128 + cb] = v;
                }
            }
        } else {  // Q / K with RoPE: pairs (cb, cb+64) share theta index cb
            int h = n0 >> 7;
#pragma unroll
            for (int nt = 0; nt < 4; nt++) {
                int cb = nt * 16 + l15;  // 0..63
#pragma unroll
                for (int r = 0; r < 4; r++) {
                    int row = rbase + r;
                    int t = row & (TT - 1);
                    float cs = cosT[t * 64 + cb];
                    float sn = sinT[t * 64 + cb];
                    float x1 = acc[mt][nt][r], x2 = acc[mt][nt + 4][r];
                    float o1 = x1 * cs - x2 * sn;
                    float o2 = x2 * cs + x1 * sn;
                    Obf[(size_t)row * N + n0 + cb] = f2bf(o1);
                    Obf[(size_t)row * N + n0 + cb + 64] = f2bf(o2);
                    if (EPI == 2) {
                        Ofp[((size_t)row * 8 + h) * 256 + cb] = o1;
                        Ofp[((size_t)row * 8 + h) * 256 + cb + 64] = o2;
                    }
                }
            }
        }
    }
}

// ------------- transpose v_heads: vh[b*2048+t][h*128+d] -> vT[(b*8+h)*128+d][t] -------------
__global__ void vtrans_k(const uint16_t* __restrict__ vh, uint16_t* __restrict__ vT) {
    __shared__ uint16_t tile[32][33];
    int bh = blockIdx.z;           // b*8+h
    int t0 = blockIdx.x * 32;
    int d0 = blockIdx.y * 32;
    int b = bh >> 3, h = bh & 7;
    int tx = threadIdx.x, ty = threadIdx.y;
#pragma unroll
    for (int i = 0; i < 4; i++) {
        int t = t0 + ty + i * 8;
        tile[ty + i * 8][tx] = vh[(size_t)(b * TT + t) * NKV + h * DK + d0 + tx];
    }
    __syncthreads();
#pragma unroll
    for (int i = 0; i < 4; i++) {
        int d = d0 + ty + i * 8;
        vT[((size_t)bh * DK + d) * TT + t0 + tx] = tile[tx][ty + i * 8];
    }
}

// ------------- flash attention v2 -------------
// Block = 4 waves = the 4 Q heads of one KV group. Each wave: 32 Q rows (2 col-tiles).
// K tile (32x128) and V^T tile (128x32) staged in LDS, shared by all 4 waves.
// S^T computed via swapped MFMA operands (A=K rows=keys, B=Q cols=qrows) so softmax
// state is per-lane (l15 = qrow); reductions are 2 shfl_xor over the quad dim.
// Causal balancing: block x processes Q-tile pair (x, 63-x) -> 65 key-tiles/block.
// T13 defer-max: skip the O-rescale (and m update) when no row's tile-max exceeds
// the running max by >8 (log2 domain; P bounded by 2^8, fine in bf16).
__global__ __launch_bounds__(256) void attn_k(
    const uint16_t* __restrict__ qh, const uint16_t* __restrict__ kh,
    const uint16_t* __restrict__ vT, uint16_t* __restrict__ ob)
{
    __shared__ __attribute__((aligned(16))) uint16_t Ks[32 * 136];   // [key][d], pad 8
    __shared__ __attribute__((aligned(16))) uint16_t Vs[128 * 40];   // [dv][key], pad 8
    __shared__ __attribute__((aligned(16))) uint16_t Ps[4 * 32 * 40];// per-wave P [qrow][key]

    int tid = threadIdx.x;
    int lane = tid & 63, wave = tid >> 6;
    int l15 = lane & 15, quad = lane >> 4;
    int kvh = blockIdx.y;
    int b = blockIdx.z;
    int hq = wave * 8 + kvh;            // G*8+H mapping: Q heads of group = {kvh, kvh+8, +16, +24}
    uint16_t* P = Ps + wave * (32 * 40);

    const uint16_t* kbase = kh + (size_t)(b * TT) * NKV + kvh * DK;
    const uint16_t* vbase = vT + ((size_t)(b * 8 + kvh) * DK) * TT;
    const float scale2 = 0.08838834764831845f * 1.4426950408889634f;  // 1/sqrt(128) * log2(e)

    int kkey = tid >> 4, kdc = tid & 15;   // K staging: 16 keys/round x 16B chunks
    int vdv = tid >> 2, vtc = tid & 3;     // V staging: 64 dv/round x 16B chunks of keys

    for (int half = 0; half < 2; half++) {
        int hh = half ? (63 - (int)blockIdx.x) : (int)blockIdx.x;
        int q0 = hh * 32;
        int ntiles = hh + 1;

        // Q B-frags (x32 B-layout: lane l15 = qrow, k = ks*32 + quad*8 + j)
        short8 qf[2][4];
#pragma unroll
        for (int qc = 0; qc < 2; qc++) {
            const uint16_t* qr = qh + (size_t)(b * TT + q0 + qc * 16 + l15) * NQ + hq * DK;
#pragma unroll
            for (int ks = 0; ks < 4; ks++)
                qf[qc][ks] = *(const short8*)(qr + ks * 32 + quad * 8);
        }

        floatx4 O[2][8];
#pragma unroll
        for (int qc = 0; qc < 2; qc++)
#pragma unroll
            for (int vt = 0; vt < 8; vt++) O[qc][vt] = floatx4{0.f, 0.f, 0.f, 0.f};
        float m_[2] = {-INFINITY, -INFINITY};
        float l_[2] = {0.f, 0.f};

        // prefetch tile 0 into regs
        short8 kst[2], vst[2];
#pragma unroll
        for (int i = 0; i < 2; i++) {
            kst[i] = *(const short8*)(kbase + (size_t)(kkey + i * 16) * NKV + kdc * 8);
            vst[i] = *(const short8*)(vbase + (size_t)(vdv + i * 64) * TT + vtc * 8);
        }

        for (int t = 0; t < ntiles; t++) {
            int kb0 = t * 32;
            __syncthreads();   // previous tile's LDS readers done
#pragma unroll
            for (int i = 0; i < 2; i++) {
                *(short8*)(Ks + (kkey + i * 16) * 136 + kdc * 8) = kst[i];
                *(short8*)(Vs + (vdv + i * 64) * 40 + vtc * 8) = vst[i];
            }
            __syncthreads();
            if (t + 1 < ntiles) {   // prefetch next tile (overlaps compute below)
                int kn = kb0 + 32;
#pragma unroll
                for (int i = 0; i < 2; i++) {
                    kst[i] = *(const short8*)(kbase + (size_t)(kn + kkey + i * 16) * NKV + kdc * 8);
                    vst[i] = *(const short8*)(vbase + (size_t)(vdv + i * 64) * TT + kn + vtc * 8);
                }
            }
            // ---- S^T = K * Q^T : C rows = keys (quad*4+r), cols = qrows (l15) ----
            floatx4 s[2][2];
            s[0][0] = floatx4{0.f,0.f,0.f,0.f}; s[0][1] = floatx4{0.f,0.f,0.f,0.f};
            s[1][0] = floatx4{0.f,0.f,0.f,0.f}; s[1][1] = floatx4{0.f,0.f,0.f,0.f};
#pragma unroll
            for (int ks = 0; ks < 4; ks++) {
                short8 kf0 = *(const short8*)(Ks + l15 * 136 + ks * 32 + quad * 8);
                short8 kf1 = *(const short8*)(Ks + (16 + l15) * 136 + ks * 32 + quad * 8);
                s[0][0] = __builtin_amdgcn_mfma_f32_16x16x32_bf16(kf0, qf[0][ks], s[0][0], 0, 0, 0);
                s[0][1] = __builtin_amdgcn_mfma_f32_16x16x32_bf16(kf0, qf[1][ks], s[0][1], 0, 0, 0);
                s[1][0] = __builtin_amdgcn_mfma_f32_16x16x32_bf16(kf1, qf[0][ks], s[1][0], 0, 0, 0);
                s[1][1] = __builtin_amdgcn_mfma_f32_16x16x32_bf16(kf1, qf[1][ks], s[1][1], 0, 0, 0);
            }
            bool maskT = (t == ntiles - 1);   // only the diagonal tile needs masking
#pragma unroll
            for (int qc = 0; qc < 2; qc++) {
                int qrow = q0 + qc * 16 + l15;
                float p[8];
#pragma unroll
                for (int krt = 0; krt < 2; krt++)
#pragma unroll
                    for (int r = 0; r < 4; r++) {
                        float v = s[krt][qc][r] * scale2;
                        if (maskT && (kb0 + krt * 16 + quad * 4 + r > qrow)) v = -INFINITY;
                        p[krt * 4 + r] = v;
                    }
                float mx = p[0];
#pragma unroll
                for (int j = 1; j < 8; j++) mx = fmaxf(mx, p[j]);
                mx = fmaxf(mx, __shfl_xor(mx, 16));
                mx = fmaxf(mx, __shfl_xor(mx, 32));
                // T13 defer-max: wave-uniform skip of the rescale pass
                bool noresc = (bool)__all(mx <= m_[qc] + 8.0f);
                float mnew = noresc ? m_[qc] : fmaxf(m_[qc], mx);
                float e[8], sum = 0.f;
#pragma unroll
                for (int j = 0; j < 8; j++) { e[j] = exp2f(p[j] - mnew); sum += e[j]; }
                sum += __shfl_xor(sum, 16);
                sum += __shfl_xor(sum, 32);
                if (noresc) {
                    l_[qc] += sum;
                } else {
                    float al = exp2f(m_[qc] - mnew);
                    l_[qc] = l_[qc] * al + sum;
                    m_[qc] = mnew;
                    // broadcast alpha from lane l15=quad*4+r for O (row-indexed) rescale
                    float ar[4];
#pragma unroll
                    for (int r = 0; r < 4; r++) ar[r] = __shfl(al, quad * 4 + r);
#pragma unroll
                    for (int vt = 0; vt < 8; vt++)
#pragma unroll
                        for (int r = 0; r < 4; r++) O[qc][vt][r] *= ar[r];
                }
                // pack P^T -> LDS as P[qrow][key] (bf16, round-to-nearest)
                bshort4 pw0, pw1;
#pragma unroll
                for (int r = 0; r < 4; r++) {
                    pw0[r] = (short)((__float_as_uint(e[r]) + 0x8000u) >> 16);
                    pw1[r] = (short)((__float_as_uint(e[4 + r]) + 0x8000u) >> 16);
                }
                *(bshort4*)(P + (qc * 16 + l15) * 40 + quad * 4) = pw0;
                *(bshort4*)(P + (qc * 16 + l15) * 40 + 16 + quad * 4) = pw1;
            }
            // ---- O += P * V^T : A = P (m=qrow), B = V^T (n=dv) ----
            short8 pf0 = *(const short8*)(P + l15 * 40 + quad * 8);
            short8 pf1 = *(const short8*)(P + (16 + l15) * 40 + quad * 8);
#pragma unroll
            for (int vt = 0; vt < 8; vt++) {
                short8 vf = *(const short8*)(Vs + (vt * 16 + l15) * 40 + quad * 8);
                O[0][vt] = __builtin_amdgcn_mfma_f32_16x16x32_bf16(pf0, vf, O[0][vt], 0, 0, 0);
                O[1][vt] = __builtin_amdgcn_mfma_f32_16x16x32_bf16(pf1, vf, O[1][vt], 0, 0, 0);
            }
        }
        // epilogue: O C-layout row = qrow (quad*4+r), col = dv (vt*16+l15)
#pragma unroll
        for (int qc = 0; qc < 2; qc++) {
            float lr[4];
#pragma unroll
            for (int r = 0; r < 4; r++) lr[r] = 1.0f / __shfl(l_[qc], quad * 4 + r);
#pragma unroll
            for (int r = 0; r < 4; r++) {
                size_t row = (size_t)(b * TT + q0 + qc * 16 + quad * 4 + r);
#pragma unroll
                for (int vt = 0; vt < 8; vt++)
                    ob[row * NQ + hq * DK + vt * 16 + l15] = f2bf(O[qc][vt][r] * lr[r]);
            }
        }
    }
}

extern "C" void kernel_launch(void* const* d_in, const int* in_sizes, int n_in,
                              void* d_out, int out_size, void* d_ws, size_t ws_size,
                              hipStream_t stream)
{
    const float* q  = (const float*)d_in[0];
    const float* k  = (const float*)d_in[1];
    const float* v  = (const float*)d_in[2];
    const float* wq = (const float*)d_in[3];
    const float* wk = (const float*)d_in[4];
    const float* wv = (const float*)d_in[5];
    const float* wo = (const float*)d_in[6];
    float* out   = (float*)d_out;                       // [2,2048,4096]
    float* cache = out + (size_t)MM * DD;               // [2,2048,8,256]

    char* ws = (char*)d_ws;
    float* cosT = (float*)ws;
    float* sinT = cosT + TT * 64;
    size_t off = 1u << 20;  // 1 MB
    const size_t SZ32 = (size_t)MM * DD * 2;   // 32 MB (bf16 4096x4096)
    const size_t SZ8  = (size_t)MM * NKV * 2;  // 8 MB  (bf16 4096x1024)
    uint16_t* wqT = (uint16_t*)(ws + off); off += SZ32;   // 4096x4096
    uint16_t* wkT = (uint16_t*)(ws + off); off += SZ8;    // 1024x4096
    uint16_t* wvT = (uint16_t*)(ws + off); off += SZ8;    // 1024x4096
    uint16_t* qb  = (uint16_t*)(ws + off); off += SZ32;
    uint16_t* kb  = (uint16_t*)(ws + off); off += SZ32;
    uint16_t* vb  = (uint16_t*)(ws + off); off += SZ32;
    uint16_t* khB = (uint16_t*)(ws + off); off += SZ8;
    uint16_t* vhB = (uint16_t*)(ws + off); off += SZ8;
    // aliases (stream-ordered reuse):
    uint16_t* vTr = wvT;  // after V GEMM done with wvT
    uint16_t* qhB = vb;   // after V GEMM done with vb
    uint16_t* woT = kb;   // after K GEMM done with kb
    uint16_t* obf = qb;   // after Q GEMM done with qb

    // 1. RoPE tables
    rope_tables_k<<<TT, 64, 0, stream>>>(cosT, sinT);
    // 2. weight convert/transpose (wq, wk, wv)
    wconv_k<<<dim3(NQ / 32, DD / 32), dim3(32, 8), 0, stream>>>(wq, wqT, DD, NQ);
    wconv_k<<<dim3(NKV / 32, DD / 32), dim3(32, 8), 0, stream>>>(wk, wkT, DD, NKV);
    wconv_k<<<dim3(NKV / 32, DD / 32), dim3(32, 8), 0, stream>>>(wv, wvT, DD, NKV);
    // 3. activation converts
    int n4 = MM * DD / 4;
    aconv_k<<<(n4 + 255) / 256, 256, 0, stream>>>((const float4*)q, (uint2*)qb, n4);
    aconv_k<<<(n4 + 255) / 256, 256, 0, stream>>>((const float4*)k, (uint2*)kb, n4);
    aconv_k<<<(n4 + 255) / 256, 256, 0, stream>>>((const float4*)v, (uint2*)vb, n4);
    // 4. V GEMM (writes vh bf16 + cache fp32)
    gemm_k<3><<<dim3(NKV / 128, MM / 128), 256, 0, stream>>>(vb, wvT, MM, NKV, DD, vhB, cache, cosT, sinT);
    // 5. K GEMM (RoPE; writes kh bf16 + cache fp32)
    gemm_k<2><<<dim3(NKV / 128, MM / 128), 256, 0, stream>>>(kb, wkT, MM, NKV, DD, khB, cache, cosT, sinT);
    // 6. Q GEMM (RoPE; writes qh bf16 into vb's space)
    gemm_k<1><<<dim3(NQ / 128, MM / 128), 256, 0, stream>>>(qb, wqT, MM, NQ, DD, qhB, nullptr, cosT, sinT);
    // 7. wo convert (into kb's space)
    wconv_k<<<dim3(DD / 32, DD / 32), dim3(32, 8), 0, stream>>>(wo, woT, DD, DD);
    // 8. V transpose (into wvT's space)
    vtrans_k<<<dim3(TT / 32, DK / 32, BB * HKV), dim3(32, 8), 0, stream>>>(vhB, vTr);
    // 9. attention (into qb's space): grid = (qtile pairs, kv heads, batch)
    attn_k<<<dim3(32, HKV, BB), 256, 0, stream>>>(qhB, khB, vTr, obf);
    // 10. output projection -> fp32 out
    gemm_k<4><<<dim3(DD / 128, MM / 128), 256, 0, stream>>>(obf, woT, MM, DD, DD, nullptr, out, cosT, sinT);
}

// Round 3
// 937.125 us; speedup vs baseline: 1.3344x; 1.2170x over previous
//
#include <hip/hip_runtime.h>
#include <hip/hip_bf16.h>
#include <cstdint>
#include <math.h>

// Problem dims (fixed)
#define BB 2
#define TT 2048
#define DD 4096
#define HQ 32
#define HKV 8
#define DK 128
#define MM (BB*TT)          // 4096 rows
#define NQ (HQ*DK)          // 4096
#define NKV (HKV*DK)        // 1024

typedef __attribute__((ext_vector_type(8))) short short8;
typedef __attribute__((ext_vector_type(4))) short bshort4;
typedef __attribute__((ext_vector_type(4))) float floatx4;

typedef unsigned int u32;
typedef __attribute__((address_space(1))) const u32 gas_u32;
typedef __attribute__((address_space(3))) u32 las_u32;

// async global->LDS, 16B per lane. LDS dest must be wave-uniform base + lane*16.
__device__ __forceinline__ void gl_lds16(const uint16_t* g, uint16_t* l) {
    __builtin_amdgcn_global_load_lds((gas_u32*)g, (las_u32*)l, 16, 0, 0);
}

__device__ inline uint16_t f2bf(float f) {
    uint32_t u = __float_as_uint(f);
    uint32_t r = (u + 0x7fffu + ((u >> 16) & 1u)) >> 16;
    return (uint16_t)r;
}

// ---------------- RoPE tables: cos/sin [2048][64] ----------------
__global__ void rope_tables_k(float* __restrict__ cosT, float* __restrict__ sinT) {
    int t = blockIdx.x;        // 0..2047
    int d = threadIdx.x;       // 0..63
    float theta = expf(-(float)d * (9.210340371976184f / 64.0f));
    float arg = (float)t * theta;
    float s, c;
    sincosf(arg, &s, &c);
    cosT[t * 64 + d] = c;
    sinT[t * 64 + d] = s;
}

// ------------- transpose-convert weights: W (K x N fp32) -> WT (N x K bf16) -------------
__global__ void wconv_k(const float* __restrict__ W, uint16_t* __restrict__ WT, int K, int N) {
    __shared__ float tile[32][33];
    int n0 = blockIdx.x * 32, k0 = blockIdx.y * 32;
    int tx = threadIdx.x, ty = threadIdx.y;  // (32, 8)
#pragma unroll
    for (int i = 0; i < 4; i++) {
        int r = k0 + ty + i * 8;
        tile[ty + i * 8][tx] = W[(size_t)r * N + n0 + tx];
    }
    __syncthreads();
#pragma unroll
    for (int i = 0; i < 4; i++) {
        int r = n0 + ty + i * 8;
        WT[(size_t)r * K + k0 + tx] = f2bf(tile[tx][ty + i * 8]);
    }
}

// ------------- activation convert fp32 -> bf16 (q,k,v in one launch) -------------
__global__ void aconv3_k(const float4* __restrict__ Xq, const float4* __restrict__ Xk,
                         const float4* __restrict__ Xv,
                         uint2* __restrict__ Yq, uint2* __restrict__ Yk, uint2* __restrict__ Yv,
                         int n4) {
    int i = blockIdx.x * blockDim.x + threadIdx.x;
    int w = blockIdx.y;
    const float4* X = (w == 0) ? Xq : (w == 1) ? Xk : Xv;
    uint2* Y = (w == 0) ? Yq : (w == 1) ? Yk : Yv;
    if (i < n4) {
        float4 v = X[i];
        uint2 o;
        o.x = (uint32_t)f2bf(v.x) | ((uint32_t)f2bf(v.y) << 16);
        o.y = (uint32_t)f2bf(v.z) | ((uint32_t)f2bf(v.w) << 16);
        Y[i] = o;
    }
}

// ------------- GEMM core: C = A(MxK) * B(NxK)^T, 128x128 tile, swizzled LDS -------------
// T2 swizzle (rule #21, both-sides): LDS chunk position c of row r holds global
// chunk c^(r&7). Source is pre-swizzled, read XORs the same pattern ->
// conflict-free ds_read_b128.
__device__ __forceinline__ void gemm_core(
    const uint16_t* __restrict__ A, const uint16_t* __restrict__ Bm, int K,
    int m0, int n0, int tid, uint16_t* As, uint16_t* Bs, floatx4 acc[2][8])
{
    int lane = tid & 63, wave = tid >> 6;
    int l15 = lane & 15, quad = lane >> 4;
#pragma unroll
    for (int a = 0; a < 2; a++)
#pragma unroll
        for (int b = 0; b < 8; b++) acc[a][b] = floatx4{0.f, 0.f, 0.f, 0.f};

    int srow = tid >> 3;
    int skc = (tid & 7) ^ (srow & 7);          // pre-swizzled global chunk index
    const uint16_t* Ag = A + (size_t)(m0 + srow) * K + skc * 8;
    const uint16_t* Bg = Bm + (size_t)(n0 + srow) * K + skc * 8;
    uint16_t* Asl = As + tid * 8;   // linear dest: chunk*16B
    uint16_t* Bsl = Bs + tid * 8;
    int rswA = l15 & 7;             // read-side XOR

    for (int k0 = 0; k0 < K; k0 += 64) {
        __syncthreads();
#pragma unroll
        for (int i = 0; i < 4; i++) {
            gl_lds16(Ag + (size_t)(i * 32) * K + k0, Asl + i * 2048);
            gl_lds16(Bg + (size_t)(i * 32) * K + k0, Bsl + i * 2048);
        }
        __syncthreads();
#pragma unroll
        for (int ks = 0; ks < 2; ks++) {
            short8 af[2], bfr[8];
#pragma unroll
            for (int mt = 0; mt < 2; mt++)
                af[mt] = *(const short8*)(As + (wave * 32 + mt * 16 + l15) * 64
                                             + (((ks << 2) | quad) ^ rswA) * 8);
#pragma unroll
            for (int nt = 0; nt < 8; nt++)
                bfr[nt] = *(const short8*)(Bs + (nt * 16 + l15) * 64
                                              + (((ks << 2) | quad) ^ rswA) * 8);
#pragma unroll
            for (int mt = 0; mt < 2; mt++)
#pragma unroll
                for (int nt = 0; nt < 8; nt++)
                    acc[mt][nt] = __builtin_amdgcn_mfma_f32_16x16x32_bf16(af[mt], bfr[nt], acc[mt][nt], 0, 0, 0);
        }
    }
}

// ------------- Q / O projection GEMM (template epilogue) -------------
// EPI: 1=Q(rope->bf16), 4=fp32 out
template <int EPI>
__global__ __launch_bounds__(256) void gemm_k(
    const uint16_t* __restrict__ A, const uint16_t* __restrict__ Bm,
    int M, int N, int K,
    uint16_t* __restrict__ Obf, float* __restrict__ Ofp,
    const float* __restrict__ cosT, const float* __restrict__ sinT)
{
    __shared__ __attribute__((aligned(16))) uint16_t As[128 * 64];
    __shared__ __attribute__((aligned(16))) uint16_t Bs[128 * 64];
    int m0 = blockIdx.y * 128;
    int n0 = blockIdx.x * 128;
    int tid = threadIdx.x;
    int lane = tid & 63, wave = tid >> 6;
    int l15 = lane & 15, quad = lane >> 4;

    floatx4 acc[2][8];
    gemm_core(A, Bm, K, m0, n0, tid, As, Bs, acc);

#pragma unroll
    for (int mt = 0; mt < 2; mt++) {
        int rbase = m0 + wave * 32 + mt * 16 + quad * 4;
        if (EPI == 4) {
#pragma unroll
            for (int nt = 0; nt < 8; nt++) {
                int c = n0 + nt * 16 + l15;
#pragma unroll
                for (int r = 0; r < 4; r++)
                    Ofp[(size_t)(rbase + r) * N + c] = acc[mt][nt][r];
            }
        } else {  // Q with RoPE: pairs (cb, cb+64) share theta index cb
#pragma unroll
            for (int nt = 0; nt < 4; nt++) {
                int cb = nt * 16 + l15;  // 0..63
#pragma unroll
                for (int r = 0; r < 4; r++) {
                    int row = rbase + r;
                    int t = row & (TT - 1);
                    float cs = cosT[t * 64 + cb];
                    float sn = sinT[t * 64 + cb];
                    float x1 = acc[mt][nt][r], x2 = acc[mt][nt + 4][r];
                    float o1 = x1 * cs - x2 * sn;
                    float o2 = x2 * cs + x1 * sn;
                    Obf[(size_t)row * N + n0 + cb] = f2bf(o1);
                    Obf[(size_t)row * N + n0 + cb + 64] = f2bf(o2);
                }
            }
        }
    }
}

// ------------- fused K+V projection GEMM: blockIdx.z = 0 -> V, 1 -> K -------------
__global__ __launch_bounds__(256) void gemm_kv_k(
    const uint16_t* __restrict__ Akk, const uint16_t* __restrict__ Avv,
    const uint16_t* __restrict__ Wk, const uint16_t* __restrict__ Wv,
    uint16_t* __restrict__ khB, uint16_t* __restrict__ vhB, float* __restrict__ cache,
    const float* __restrict__ cosT, const float* __restrict__ sinT)
{
    __shared__ __attribute__((aligned(16))) uint16_t As[128 * 64];
    __shared__ __attribute__((aligned(16))) uint16_t Bs[128 * 64];
    bool isK = (blockIdx.z == 1);
    const uint16_t* A = isK ? Akk : Avv;
    const uint16_t* Bm = isK ? Wk : Wv;
    int m0 = blockIdx.y * 128;
    int n0 = blockIdx.x * 128;
    int tid = threadIdx.x;
    int lane = tid & 63, wave = tid >> 6;
    int l15 = lane & 15, quad = lane >> 4;

    floatx4 acc[2][8];
    gemm_core(A, Bm, DD, m0, n0, tid, As, Bs, acc);

    int h = n0 >> 7;
#pragma unroll
    for (int mt = 0; mt < 2; mt++) {
        int rbase = m0 + wave * 32 + mt * 16 + quad * 4;
        if (!isK) {  // V: bf16 vh + fp32 cache[...,128+d]
#pragma unroll
            for (int nt = 0; nt < 8; nt++) {
                int cb = nt * 16 + l15;  // d in 0..127
#pragma unroll
                for (int r = 0; r < 4; r++) {
                    int row = rbase + r;
                    float v = acc[mt][nt][r];
                    vhB[(size_t)row * NKV + n0 + cb] = f2bf(v);
                    cache[((size_t)row * 8 + h) * 256 + 128 + cb] = v;
                }
            }
        } else {  // K with RoPE: bf16 kh + fp32 cache[...,d]
#pragma unroll
            for (int nt = 0; nt < 4; nt++) {
                int cb = nt * 16 + l15;  // 0..63
#pragma unroll
                for (int r = 0; r < 4; r++) {
                    int row = rbase + r;
                    int t = row & (TT - 1);
                    float cs = cosT[t * 64 + cb];
                    float sn = sinT[t * 64 + cb];
                    float x1 = acc[mt][nt][r], x2 = acc[mt][nt + 4][r];
                    float o1 = x1 * cs - x2 * sn;
                    float o2 = x2 * cs + x1 * sn;
                    khB[(size_t)row * NKV + n0 + cb] = f2bf(o1);
                    khB[(size_t)row * NKV + n0 + cb + 64] = f2bf(o2);
                    cache[((size_t)row * 8 + h) * 256 + cb] = o1;
                    cache[((size_t)row * 8 + h) * 256 + cb + 64] = o2;
                }
            }
        }
    }
}

// ------------- transpose v_heads: vh[b*2048+t][h*128+d] -> vT[(b*8+h)*128+d][t] -------------
__global__ void vtrans_k(const uint16_t* __restrict__ vh, uint16_t* __restrict__ vT) {
    __shared__ uint16_t tile[32][33];
    int bh = blockIdx.z;           // b*8+h
    int t0 = blockIdx.x * 32;
    int d0 = blockIdx.y * 32;
    int b = bh >> 3, h = bh & 7;
    int tx = threadIdx.x, ty = threadIdx.y;
#pragma unroll
    for (int i = 0; i < 4; i++) {
        int t = t0 + ty + i * 8;
        tile[ty + i * 8][tx] = vh[(size_t)(b * TT + t) * NKV + h * DK + d0 + tx];
    }
    __syncthreads();
#pragma unroll
    for (int i = 0; i < 4; i++) {
        int d = d0 + ty + i * 8;
        vT[((size_t)bh * DK + d) * TT + t0 + tx] = tile[tx][ty + i * 8];
    }
}

// ------------- flash attention v2 — 8-wave / 16-qrow-per-wave (occupancy fix) -------------
// Block = 8 waves (512 thr) = 4 Q heads x 2 row-halves of one KV group's 32-row Q tile.
// wave: sub = wave&1 (row half), hg = wave>>1 (head). Per wave: 16 Q rows in regs,
// O[8] accum (32 VGPR) -> VGPR ~110, __launch_bounds__(512,4) => 2 blocks/CU = 16 waves/CU.
// K tile (32x128) and V^T tile (128x32) staged in LDS, shared by all 8 waves.
// S^T via swapped MFMA operands (softmax state per-lane, l15 = qrow).
// Causal balancing: block x processes Q-tile pair (x, 63-x) -> 65 key-tiles/block.
// T13 defer-max + T5 setprio around MFMA clusters.
__global__ __launch_bounds__(512, 4) void attn_k(
    const uint16_t* __restrict__ qh, const uint16_t* __restrict__ kh,
    const uint16_t* __restrict__ vT, uint16_t* __restrict__ ob)
{
    __shared__ __attribute__((aligned(16))) uint16_t Ks[32 * 136];   // [key][d], pad 8
    __shared__ __attribute__((aligned(16))) uint16_t Vs[128 * 40];   // [dv][key], pad 8
    __shared__ __attribute__((aligned(16))) uint16_t Ps[8 * 16 * 40];// per-wave P [qrow][key]

    int tid = threadIdx.x;
    int lane = tid & 63, wave = tid >> 6;     // 0..7
    int l15 = lane & 15, quad = lane >> 4;
    int sub = wave & 1, hg = wave >> 1;       // row-half, head-group
    int kvh = blockIdx.y;
    int b = blockIdx.z;
    int hq = hg * 8 + kvh;                    // Q heads of group = {kvh, kvh+8, +16, +24}
    uint16_t* P = Ps + wave * (16 * 40);

    const uint16_t* kbase = kh + (size_t)(b * TT) * NKV + kvh * DK;
    const uint16_t* vbase = vT + ((size_t)(b * 8 + kvh) * DK) * TT;
    const float scale2 = 0.08838834764831845f * 1.4426950408889634f;  // 1/sqrt(128) * log2(e)

    int kkey = tid >> 4, kdc = tid & 15;   // K staging: 32 keys x 16B chunks (512 thr)
    int vdv = tid >> 2, vtc = tid & 3;     // V staging: 128 dv x 4 chunks

    for (int half = 0; half < 2; half++) {
        int hh = half ? (63 - (int)blockIdx.x) : (int)blockIdx.x;
        int q0 = hh * 32;
        int ntiles = hh + 1;

        // Q B-frags (lane l15 = qrow, k = ks*32 + quad*8 + j)
        short8 qf[4];
        {
            const uint16_t* qr = qh + (size_t)(b * TT + q0 + sub * 16 + l15) * NQ + hq * DK;
#pragma unroll
            for (int ks = 0; ks < 4; ks++)
                qf[ks] = *(const short8*)(qr + ks * 32 + quad * 8);
        }

        floatx4 O[8];
#pragma unroll
        for (int vt = 0; vt < 8; vt++) O[vt] = floatx4{0.f, 0.f, 0.f, 0.f};
        float m_ = -INFINITY;
        float l_ = 0.f;

        // prefetch tile 0 into regs
        short8 kst = *(const short8*)(kbase + (size_t)kkey * NKV + kdc * 8);
        short8 vst = *(const short8*)(vbase + (size_t)vdv * TT + vtc * 8);

        for (int t = 0; t < ntiles; t++) {
            int kb0 = t * 32;
            __syncthreads();   // previous tile's LDS readers done
            *(short8*)(Ks + kkey * 136 + kdc * 8) = kst;
            *(short8*)(Vs + vdv * 40 + vtc * 8) = vst;
            __syncthreads();
            if (t + 1 < ntiles) {   // prefetch next tile (overlaps compute below)
                int kn = kb0 + 32;
                kst = *(const short8*)(kbase + (size_t)(kn + kkey) * NKV + kdc * 8);
                vst = *(const short8*)(vbase + (size_t)vdv * TT + kn + vtc * 8);
            }
            // ---- S^T = K * Q^T : C rows = keys (quad*4+r), cols = qrows (l15) ----
            floatx4 s[2];
            s[0] = floatx4{0.f,0.f,0.f,0.f};
            s[1] = floatx4{0.f,0.f,0.f,0.f};
            __builtin_amdgcn_s_setprio(1);
#pragma unroll
            for (int ks = 0; ks < 4; ks++) {
                short8 kf0 = *(const short8*)(Ks + l15 * 136 + ks * 32 + quad * 8);
                short8 kf1 = *(const short8*)(Ks + (16 + l15) * 136 + ks * 32 + quad * 8);
                s[0] = __builtin_amdgcn_mfma_f32_16x16x32_bf16(kf0, qf[ks], s[0], 0, 0, 0);
                s[1] = __builtin_amdgcn_mfma_f32_16x16x32_bf16(kf1, qf[ks], s[1], 0, 0, 0);
            }
            __builtin_amdgcn_s_setprio(0);
            bool maskT = (t == ntiles - 1);   // only the diagonal tile needs masking
            int qrow = q0 + sub * 16 + l15;
            float p[8];
#pragma unroll
            for (int krt = 0; krt < 2; krt++)
#pragma unroll
                for (int r = 0; r < 4; r++) {
                    float v = s[krt][r] * scale2;
                    if (maskT && (kb0 + krt * 16 + quad * 4 + r > qrow)) v = -INFINITY;
                    p[krt * 4 + r] = v;
                }
            float mx = p[0];
#pragma unroll
            for (int j = 1; j < 8; j++) mx = fmaxf(mx, p[j]);
            mx = fmaxf(mx, __shfl_xor(mx, 16));
            mx = fmaxf(mx, __shfl_xor(mx, 32));
            // T13 defer-max: wave-uniform skip of the rescale pass
            bool noresc = (bool)__all(mx <= m_ + 8.0f);
            float mnew = noresc ? m_ : fmaxf(m_, mx);
            float e[8], sum = 0.f;
#pragma unroll
            for (int j = 0; j < 8; j++) { e[j] = exp2f(p[j] - mnew); sum += e[j]; }
            sum += __shfl_xor(sum, 16);
            sum += __shfl_xor(sum, 32);
            if (noresc) {
                l_ += sum;
            } else {
                float al = exp2f(m_ - mnew);
                l_ = l_ * al + sum;
                m_ = mnew;
                // broadcast alpha from lane l15=quad*4+r for O (row-indexed) rescale
                float ar[4];
#pragma unroll
                for (int r = 0; r < 4; r++) ar[r] = __shfl(al, quad * 4 + r);
#pragma unroll
                for (int vt = 0; vt < 8; vt++)
#pragma unroll
                    for (int r = 0; r < 4; r++) O[vt][r] *= ar[r];
            }
            // pack P^T -> LDS as P[qrow][key] (bf16, round-to-nearest)
            bshort4 pw0, pw1;
#pragma unroll
            for (int r = 0; r < 4; r++) {
                pw0[r] = (short)((__float_as_uint(e[r]) + 0x8000u) >> 16);
                pw1[r] = (short)((__float_as_uint(e[4 + r]) + 0x8000u) >> 16);
            }
            *(bshort4*)(P + l15 * 40 + quad * 4) = pw0;
            *(bshort4*)(P + l15 * 40 + 16 + quad * 4) = pw1;
            // ---- O += P * V^T : A = P (m=qrow), B = V^T (n=dv) ----
            short8 pf = *(const short8*)(P + l15 * 40 + quad * 8);
            __builtin_amdgcn_s_setprio(1);
#pragma unroll
            for (int vt = 0; vt < 8; vt++) {
                short8 vf = *(const short8*)(Vs + (vt * 16 + l15) * 40 + quad * 8);
                O[vt] = __builtin_amdgcn_mfma_f32_16x16x32_bf16(pf, vf, O[vt], 0, 0, 0);
            }
            __builtin_amdgcn_s_setprio(0);
        }
        // epilogue: O C-layout row = qrow (quad*4+r), col = dv (vt*16+l15)
        float lr[4];
#pragma unroll
        for (int r = 0; r < 4; r++) lr[r] = 1.0f / __shfl(l_, quad * 4 + r);
#pragma unroll
        for (int r = 0; r < 4; r++) {
            size_t row = (size_t)(b * TT + q0 + sub * 16 + quad * 4 + r);
#pragma unroll
            for (int vt = 0; vt < 8; vt++)
                ob[row * NQ + hq * DK + vt * 16 + l15] = f2bf(O[vt][r] * lr[r]);
        }
    }
}

extern "C" void kernel_launch(void* const* d_in, const int* in_sizes, int n_in,
                              void* d_out, int out_size, void* d_ws, size_t ws_size,
                              hipStream_t stream)
{
    const float* q  = (const float*)d_in[0];
    const float* k  = (const float*)d_in[1];
    const float* v  = (const float*)d_in[2];
    const float* wq = (const float*)d_in[3];
    const float* wk = (const float*)d_in[4];
    const float* wv = (const float*)d_in[5];
    const float* wo = (const float*)d_in[6];
    float* out   = (float*)d_out;                       // [2,2048,4096]
    float* cache = out + (size_t)MM * DD;               // [2,2048,8,256]

    char* ws = (char*)d_ws;
    float* cosT = (float*)ws;
    float* sinT = cosT + TT * 64;
    size_t off = 1u << 20;  // 1 MB
    const size_t SZ32 = (size_t)MM * DD * 2;   // 32 MB (bf16 4096x4096)
    const size_t SZ8  = (size_t)MM * NKV * 2;  // 8 MB  (bf16 4096x1024)
    uint16_t* wqT = (uint16_t*)(ws + off); off += SZ32;   // 4096x4096
    uint16_t* wkT = (uint16_t*)(ws + off); off += SZ8;    // 1024x4096
    uint16_t* wvT = (uint16_t*)(ws + off); off += SZ8;    // 1024x4096
    uint16_t* qb  = (uint16_t*)(ws + off); off += SZ32;
    uint16_t* kb  = (uint16_t*)(ws + off); off += SZ32;
    uint16_t* vb  = (uint16_t*)(ws + off); off += SZ32;
    uint16_t* khB = (uint16_t*)(ws + off); off += SZ8;
    uint16_t* vhB = (uint16_t*)(ws + off); off += SZ8;
    // aliases (stream-ordered reuse):
    uint16_t* vTr = wvT;  // after KV GEMM done with wvT
    uint16_t* qhB = vb;   // after KV GEMM done with vb
    uint16_t* woT = kb;   // after KV GEMM done with kb
    uint16_t* obf = qb;   // after Q GEMM done with qb

    // 1. RoPE tables
    rope_tables_k<<<TT, 64, 0, stream>>>(cosT, sinT);
    // 2. weight convert/transpose (wq, wk, wv)
    wconv_k<<<dim3(NQ / 32, DD / 32), dim3(32, 8), 0, stream>>>(wq, wqT, DD, NQ);
    wconv_k<<<dim3(NKV / 32, DD / 32), dim3(32, 8), 0, stream>>>(wk, wkT, DD, NKV);
    wconv_k<<<dim3(NKV / 32, DD / 32), dim3(32, 8), 0, stream>>>(wv, wvT, DD, NKV);
    // 3. activation converts (fused q,k,v)
    int n4 = MM * DD / 4;
    aconv3_k<<<dim3((n4 + 255) / 256, 3), 256, 0, stream>>>(
        (const float4*)q, (const float4*)k, (const float4*)v,
        (uint2*)qb, (uint2*)kb, (uint2*)vb, n4);
    // 4. fused K+V GEMM (z=0: V writes vh bf16 + cache; z=1: K rope + cache)
    gemm_kv_k<<<dim3(NKV / 128, MM / 128, 2), 256, 0, stream>>>(
        kb, vb, wkT, wvT, khB, vhB, cache, cosT, sinT);
    // 5. Q GEMM (RoPE; writes qh bf16 into vb's space)
    gemm_k<1><<<dim3(NQ / 128, MM / 128), 256, 0, stream>>>(qb, wqT, MM, NQ, DD, qhB, nullptr, cosT, sinT);
    // 6. wo convert (into kb's space)
    wconv_k<<<dim3(DD / 32, DD / 32), dim3(32, 8), 0, stream>>>(wo, woT, DD, DD);
    // 7. V transpose (into wvT's space)
    vtrans_k<<<dim3(TT / 32, DK / 32, BB * HKV), dim3(32, 8), 0, stream>>>(vhB, vTr);
    // 8. attention (into qb's space): grid = (qtile pairs, kv heads, batch), 512 thr
    attn_k<<<dim3(32, HKV, BB), 512, 0, stream>>>(qhB, khB, vTr, obf);
    // 9. output projection -> fp32 out
    gemm_k<4><<<dim3(DD / 128, MM / 128), 256, 0, stream>>>(obf, woT, MM, DD, DD, nullptr, out, cosT, sinT);
}

// Round 4
// 887.863 us; speedup vs baseline: 1.4084x; 1.0555x over previous
//
#include <hip/hip_runtime.h>
#include <hip/hip_bf16.h>
#include <cstdint>
#include <math.h>

// Problem dims (fixed)
#define BB 2
#define TT 2048
#define DD 4096
#define HQ 32
#define HKV 8
#define DK 128
#define MM (BB*TT)          // 4096 rows
#define NQ (HQ*DK)          // 4096
#define NKV (HKV*DK)        // 1024

typedef __attribute__((ext_vector_type(8))) short short8;
typedef __attribute__((ext_vector_type(4))) short bshort4;
typedef __attribute__((ext_vector_type(4))) float floatx4;

typedef unsigned int u32;
typedef __attribute__((address_space(1))) const u32 gas_u32;
typedef __attribute__((address_space(3))) u32 las_u32;

// async global->LDS, 16B per lane. LDS dest must be wave-uniform base + lane*16.
__device__ __forceinline__ void gl_lds16(const uint16_t* g, uint16_t* l) {
    __builtin_amdgcn_global_load_lds((gas_u32*)g, (las_u32*)l, 16, 0, 0);
}

__device__ inline uint16_t f2bf(float f) {
    uint32_t u = __float_as_uint(f);
    uint32_t r = (u + 0x7fffu + ((u >> 16) & 1u)) >> 16;
    return (uint16_t)r;
}

#define ASM_VMCNT8 asm volatile("s_waitcnt vmcnt(8)" ::: "memory")
#define ASM_VMCNT0 asm volatile("s_waitcnt vmcnt(0)" ::: "memory")
#define ASM_LGKM0  asm volatile("s_waitcnt lgkmcnt(0)" ::: "memory")
#define RAW_BAR    __builtin_amdgcn_s_barrier()
#define SCHED_B    __builtin_amdgcn_sched_barrier(0)

// bijective XCD swizzle for nwg%8==0 grids
__device__ __forceinline__ void swz_xy(int gx, int nwg, int& bx, int& by) {
    int idx = by * gx + bx;
    int cpx = nwg >> 3;
    idx = (idx & 7) * cpx + (idx >> 3);
    bx = idx % gx;
    by = idx / gx;
}

// ---------------- RoPE tables: cos/sin [2048][64] ----------------
__global__ void rope_tables_k(float* __restrict__ cosT, float* __restrict__ sinT) {
    int t = blockIdx.x;        // 0..2047
    int d = threadIdx.x;       // 0..63
    float theta = expf(-(float)d * (9.210340371976184f / 64.0f));
    float arg = (float)t * theta;
    float s, c;
    sincosf(arg, &s, &c);
    cosT[t * 64 + d] = c;
    sinT[t * 64 + d] = s;
}

// ------------- transpose-convert weights: W (K x N fp32) -> WT (N x K bf16) -------------
// PERM: swap bits 5<->6 of the output-column index (head-local). With the 256^2 GEMM's
// 64-col-per-wave layout this places both halves of each RoPE pair (d, d+64) in the
// same wave's accumulator (involution; epilogue applies the inverse when storing).
template <bool PERM>
__global__ void wconv_k(const float* __restrict__ W, uint16_t* __restrict__ WT, int K, int N) {
    __shared__ float tile[32][33];
    int n0 = blockIdx.x * 32, k0 = blockIdx.y * 32;
    int tx = threadIdx.x, ty = threadIdx.y;  // (32, 8)
#pragma unroll
    for (int i = 0; i < 4; i++) {
        int r = k0 + ty + i * 8;
        tile[ty + i * 8][tx] = W[(size_t)r * N + n0 + tx];
    }
    __syncthreads();
#pragma unroll
    for (int i = 0; i < 4; i++) {
        int r = n0 + ty + i * 8;
        int rp = r;
        if (PERM) rp = (r & ~96) | (((r >> 5) & 1) << 6) | (((r >> 6) & 1) << 5);
        WT[(size_t)rp * K + k0 + tx] = f2bf(tile[tx][ty + i * 8]);
    }
}

// ------------- activation convert fp32 -> bf16 (q,k,v in one launch) -------------
__global__ void aconv3_k(const float4* __restrict__ Xq, const float4* __restrict__ Xk,
                         const float4* __restrict__ Xv,
                         uint2* __restrict__ Yq, uint2* __restrict__ Yk, uint2* __restrict__ Yv,
                         int n4) {
    int i = blockIdx.x * blockDim.x + threadIdx.x;
    int w = blockIdx.y;
    const float4* X = (w == 0) ? Xq : (w == 1) ? Xk : Xv;
    uint2* Y = (w == 0) ? Yq : (w == 1) ? Yk : Yv;
    if (i < n4) {
        float4 v = X[i];
        uint2 o;
        o.x = (uint32_t)f2bf(v.x) | ((uint32_t)f2bf(v.y) << 16);
        o.y = (uint32_t)f2bf(v.z) | ((uint32_t)f2bf(v.w) << 16);
        Y[i] = o;
    }
}

// ================= 256x256 GEMM core, BK=64, 8 waves, double-buffered LDS =================
// T3+T4: loads for K-tile t+1 are ISSUED at the start of tile t (into the other buffer)
// and waited with counted vmcnt(8) at the start of tile t+1 -> a full K-tile of MFMA
// overlaps every staging round. Raw s_barrier (no vmcnt(0) drain) in the main loop.
// T2 swizzle: LDS 16B-chunk position c of row r holds global chunk c^(r&7); source
// pre-swizzled, read XORs (l15&7) -> conflict-free ds_read_b128.
// Per-wave output 128x64: acc[8][4] (qm*4+fm, qn*2+fn).
__device__ __forceinline__ void gemm256_core(
    const uint16_t* __restrict__ A, const uint16_t* __restrict__ Bm, int K,
    int m0, int n0, int tid, uint16_t* As2, uint16_t* Bs2, floatx4 acc[8][4])
{
    int lane = tid & 63;
    int l15 = lane & 15, quad = lane >> 4;
    int wave = tid >> 6;
    int wm = wave >> 2, wn = wave & 3;

#pragma unroll
    for (int a = 0; a < 8; a++)
#pragma unroll
        for (int b = 0; b < 4; b++) acc[a][b] = floatx4{0.f, 0.f, 0.f, 0.f};

    // staging: 512 thr; per matrix 256 rows x 8 chunks = 2048 chunks; 4 per thread.
    int srow = tid >> 3;                        // 0..63 (+i*64)
    int skc = (tid & 7) ^ (srow & 7);           // pre-swizzled source chunk
    const uint16_t* Ab = A + (size_t)(m0 + srow) * K + skc * 8;
    const uint16_t* Bb = Bm + (size_t)(n0 + srow) * K + skc * 8;
    uint16_t* AsD = As2 + tid * 8;              // + buf*16384 + i*4096
    uint16_t* BsD = Bs2 + tid * 8;
    int rsw = l15 & 7;                          // read-side XOR

    const int NT = K / 64;

    // prologue: stage tile 0 -> buf 0
#pragma unroll
    for (int i = 0; i < 4; i++) {
        gl_lds16(Ab + (size_t)(i * 64) * K, AsD + i * 4096);
        gl_lds16(Bb + (size_t)(i * 64) * K, BsD + i * 4096);
    }

    for (int t = 0; t < NT; ++t) {
        const uint16_t* bufA = As2 + (t & 1) * 16384;
        const uint16_t* bufB = Bs2 + (t & 1) * 16384;
        ASM_LGKM0;           // own ds_reads of previous tile retired
        SCHED_B;
        RAW_BAR;             // all waves done reading buf[(t+1)&1]'s old tile
        SCHED_B;
        if (t + 1 < NT) {    // issue next tile's loads into the other buffer
            int k0n = (t + 1) * 64;
            uint16_t* dA = As2 + ((t + 1) & 1) * 16384 + tid * 8;
            uint16_t* dB = Bs2 + ((t + 1) & 1) * 16384 + tid * 8;
#pragma unroll
            for (int i = 0; i < 4; i++) {
                gl_lds16(Ab + (size_t)(i * 64) * K + k0n, dA + i * 4096);
                gl_lds16(Bb + (size_t)(i * 64) * K + k0n, dB + i * 4096);
            }
            ASM_VMCNT8;      // tile t's 8 loads done; t+1's 8 stay in flight
        } else {
            ASM_VMCNT0;
        }
        SCHED_B;
        RAW_BAR;             // all waves' tile-t staging visible
        SCHED_B;

        // compute tile t: 4 quadrant phases
#pragma unroll
        for (int qm = 0; qm < 2; qm++) {
            short8 af[4][2];
#pragma unroll
            for (int fm = 0; fm < 4; fm++)
#pragma unroll
                for (int ks = 0; ks < 2; ks++) {
                    int row = wm * 128 + qm * 64 + fm * 16 + l15;
                    af[fm][ks] = *(const short8*)(bufA + row * 64 + ((((ks << 2) | quad) ^ rsw) << 3));
                }
#pragma unroll
            for (int qn = 0; qn < 2; qn++) {
                short8 bfv[2][2];
#pragma unroll
                for (int fn = 0; fn < 2; fn++)
#pragma unroll
                    for (int ks = 0; ks < 2; ks++) {
                        int row = wn * 64 + qn * 32 + fn * 16 + l15;
                        bfv[fn][ks] = *(const short8*)(bufB + row * 64 + ((((ks << 2) | quad) ^ rsw) << 3));
                    }
                __builtin_amdgcn_s_setprio(1);
#pragma unroll
                for (int ks = 0; ks < 2; ks++)
#pragma unroll
                    for (int fm = 0; fm < 4; fm++)
#pragma unroll
                        for (int fn = 0; fn < 2; fn++)
                            acc[qm * 4 + fm][qn * 2 + fn] = __builtin_amdgcn_mfma_f32_16x16x32_bf16(
                                af[fm][ks], bfv[fn][ks], acc[qm * 4 + fm][qn * 2 + fn], 0, 0, 0);
                __builtin_amdgcn_s_setprio(0);
            }
        }
    }
}

// ------------- Q / O projection GEMM (256^2). EPI: 1=Q(rope->bf16, permuted W), 4=fp32 out -------------
template <int EPI>
__global__ __launch_bounds__(512, 2) void gemm256_k(
    const uint16_t* __restrict__ A, const uint16_t* __restrict__ Bm,
    int M, int N, int K,
    uint16_t* __restrict__ Obf, float* __restrict__ Ofp,
    const float* __restrict__ cosT, const float* __restrict__ sinT)
{
    __shared__ __attribute__((aligned(16))) uint16_t AB[4 * 16384];  // 128 KB
    int bx = blockIdx.x, by = blockIdx.y;
    swz_xy(gridDim.x, gridDim.x * gridDim.y, bx, by);
    int m0 = by * 256, n0 = bx * 256;
    int tid = threadIdx.x;
    int lane = tid & 63, wave = tid >> 6;
    int l15 = lane & 15, quad = lane >> 4;
    int wm = wave >> 2, wn = wave & 3;

    floatx4 acc[8][4];
    gemm256_core(A, Bm, K, m0, n0, tid, AB, AB + 2 * 16384, acc);

    if (EPI == 4) {
#pragma unroll
        for (int qm = 0; qm < 2; qm++)
#pragma unroll
            for (int fm = 0; fm < 4; fm++) {
                int rbase = m0 + wm * 128 + qm * 64 + fm * 16 + quad * 4;
#pragma unroll
                for (int qn = 0; qn < 2; qn++)
#pragma unroll
                    for (int fn = 0; fn < 2; fn++) {
                        int c = n0 + wn * 64 + qn * 32 + fn * 16 + l15;
#pragma unroll
                        for (int r = 0; r < 4; r++)
                            Ofp[(size_t)(rbase + r) * N + c] = acc[qm * 4 + fm][qn * 2 + fn][r];
                    }
            }
    } else {
        // Q RoPE epilogue. Wave's 64 phys cols (bit-5/6-swapped space): qn=0 holds x1
        // (logical d = j*32 + fn*16 + l15), qn=1 holds x2 (logical d+64).
        int c64 = n0 + wn * 64;
        int h = c64 >> 7;
        int j = (c64 >> 6) & 1;
#pragma unroll
        for (int qm = 0; qm < 2; qm++)
#pragma unroll
            for (int fm = 0; fm < 4; fm++) {
                int rbase = m0 + wm * 128 + qm * 64 + fm * 16 + quad * 4;
#pragma unroll
                for (int fn = 0; fn < 2; fn++) {
                    int d = j * 32 + fn * 16 + l15;
#pragma unroll
                    for (int r = 0; r < 4; r++) {
                        int row = rbase + r;
                        int t = row & (TT - 1);
                        float cs = cosT[t * 64 + d];
                        float sn = sinT[t * 64 + d];
                        float x1 = acc[qm * 4 + fm][fn][r];
                        float x2 = acc[qm * 4 + fm][2 + fn][r];
                        float o1 = x1 * cs - x2 * sn;
                        float o2 = x2 * cs + x1 * sn;
                        Obf[(size_t)row * N + h * 128 + d] = f2bf(o1);
                        Obf[(size_t)row * N + h * 128 + d + 64] = f2bf(o2);
                    }
                }
            }
    }
}

// ------------- fused K+V projection GEMM (256^2): blockIdx.z = 0 -> V, 1 -> K -------------
__global__ __launch_bounds__(512, 2) void gemm256_kv_k(
    const uint16_t* __restrict__ Akk, const uint16_t* __restrict__ Avv,
    const uint16_t* __restrict__ Wk, const uint16_t* __restrict__ Wv,
    uint16_t* __restrict__ khB, uint16_t* __restrict__ vhB, float* __restrict__ cache,
    const float* __restrict__ cosT, const float* __restrict__ sinT)
{
    __shared__ __attribute__((aligned(16))) uint16_t AB[4 * 16384];  // 128 KB
    bool isK = (blockIdx.z == 1);
    const uint16_t* A = isK ? Akk : Avv;
    const uint16_t* Bm = isK ? Wk : Wv;
    int bx = blockIdx.x, by = blockIdx.y;
    swz_xy(gridDim.x, gridDim.x * gridDim.y, bx, by);
    int m0 = by * 256, n0 = bx * 256;
    int tid = threadIdx.x;
    int lane = tid & 63, wave = tid >> 6;
    int l15 = lane & 15, quad = lane >> 4;
    int wm = wave >> 2, wn = wave & 3;

    floatx4 acc[8][4];
    gemm256_core(A, Bm, DD, m0, n0, tid, AB, AB + 2 * 16384, acc);

    if (!isK) {  // V: bf16 vh + fp32 cache[...,128+d]
#pragma unroll
        for (int qm = 0; qm < 2; qm++)
#pragma unroll
            for (int fm = 0; fm < 4; fm++) {
                int rbase = m0 + wm * 128 + qm * 64 + fm * 16 + quad * 4;
#pragma unroll
                for (int qn = 0; qn < 2; qn++)
#pragma unroll
                    for (int fn = 0; fn < 2; fn++) {
                        int c = n0 + wn * 64 + qn * 32 + fn * 16 + l15;
                        int h = c >> 7, cb = c & 127;
#pragma unroll
                        for (int r = 0; r < 4; r++) {
                            int row = rbase + r;
                            float v = acc[qm * 4 + fm][qn * 2 + fn][r];
                            vhB[(size_t)row * NKV + c] = f2bf(v);
                            cache[((size_t)row * 8 + h) * 256 + 128 + cb] = v;
                        }
                    }
            }
    } else {  // K with RoPE (permuted W): bf16 kh + fp32 cache, both logical layout
        int c64 = n0 + wn * 64;
        int h = c64 >> 7;
        int j = (c64 >> 6) & 1;
#pragma unroll
        for (int qm = 0; qm < 2; qm++)
#pragma unroll
            for (int fm = 0; fm < 4; fm++) {
                int rbase = m0 + wm * 128 + qm * 64 + fm * 16 + quad * 4;
#pragma unroll
                for (int fn = 0; fn < 2; fn++) {
                    int d = j * 32 + fn * 16 + l15;
#pragma unroll
                    for (int r = 0; r < 4; r++) {
                        int row = rbase + r;
                        int t = row & (TT - 1);
                        float cs = cosT[t * 64 + d];
                        float sn = sinT[t * 64 + d];
                        float x1 = acc[qm * 4 + fm][fn][r];
                        float x2 = acc[qm * 4 + fm][2 + fn][r];
                        float o1 = x1 * cs - x2 * sn;
                        float o2 = x2 * cs + x1 * sn;
                        khB[(size_t)row * NKV + h * 128 + d] = f2bf(o1);
                        khB[(size_t)row * NKV + h * 128 + d + 64] = f2bf(o2);
                        cache[((size_t)row * 8 + h) * 256 + d] = o1;
                        cache[((size_t)row * 8 + h) * 256 + d + 64] = o2;
                    }
                }
            }
    }
}

// ------------- transpose v_heads: vh[b*2048+t][h*128+d] -> vT[(b*8+h)*128+d][t] -------------
__global__ void vtrans_k(const uint16_t* __restrict__ vh, uint16_t* __restrict__ vT) {
    __shared__ uint16_t tile[32][33];
    int bh = blockIdx.z;           // b*8+h
    int t0 = blockIdx.x * 32;
    int d0 = blockIdx.y * 32;
    int b = bh >> 3, h = bh & 7;
    int tx = threadIdx.x, ty = threadIdx.y;
#pragma unroll
    for (int i = 0; i < 4; i++) {
        int t = t0 + ty + i * 8;
        tile[ty + i * 8][tx] = vh[(size_t)(b * TT + t) * NKV + h * DK + d0 + tx];
    }
    __syncthreads();
#pragma unroll
    for (int i = 0; i < 4; i++) {
        int d = d0 + ty + i * 8;
        vT[((size_t)bh * DK + d) * TT + t0 + tx] = tile[tx][ty + i * 8];
    }
}

// ------------- flash attention v2 — 8-wave / 16-qrow-per-wave -------------
__global__ __launch_bounds__(512, 4) void attn_k(
    const uint16_t* __restrict__ qh, const uint16_t* __restrict__ kh,
    const uint16_t* __restrict__ vT, uint16_t* __restrict__ ob)
{
    __shared__ __attribute__((aligned(16))) uint16_t Ks[32 * 136];   // [key][d], pad 8
    __shared__ __attribute__((aligned(16))) uint16_t Vs[128 * 40];   // [dv][key], pad 8
    __shared__ __attribute__((aligned(16))) uint16_t Ps[8 * 16 * 40];// per-wave P [qrow][key]

    int tid = threadIdx.x;
    int lane = tid & 63, wave = tid >> 6;     // 0..7
    int l15 = lane & 15, quad = lane >> 4;
    int sub = wave & 1, hg = wave >> 1;       // row-half, head-group
    int kvh = blockIdx.y;
    int b = blockIdx.z;
    int hq = hg * 8 + kvh;                    // Q heads of group = {kvh, kvh+8, +16, +24}
    uint16_t* P = Ps + wave * (16 * 40);

    const uint16_t* kbase = kh + (size_t)(b * TT) * NKV + kvh * DK;
    const uint16_t* vbase = vT + ((size_t)(b * 8 + kvh) * DK) * TT;
    const float scale2 = 0.08838834764831845f * 1.4426950408889634f;  // 1/sqrt(128) * log2(e)

    int kkey = tid >> 4, kdc = tid & 15;   // K staging: 32 keys x 16B chunks (512 thr)
    int vdv = tid >> 2, vtc = tid & 3;     // V staging: 128 dv x 4 chunks

    for (int half = 0; half < 2; half++) {
        int hh = half ? (63 - (int)blockIdx.x) : (int)blockIdx.x;
        int q0 = hh * 32;
        int ntiles = hh + 1;

        // Q B-frags (lane l15 = qrow, k = ks*32 + quad*8 + j)
        short8 qf[4];
        {
            const uint16_t* qr = qh + (size_t)(b * TT + q0 + sub * 16 + l15) * NQ + hq * DK;
#pragma unroll
            for (int ks = 0; ks < 4; ks++)
                qf[ks] = *(const short8*)(qr + ks * 32 + quad * 8);
        }

        floatx4 O[8];
#pragma unroll
        for (int vt = 0; vt < 8; vt++) O[vt] = floatx4{0.f, 0.f, 0.f, 0.f};
        float m_ = -INFINITY;
        float l_ = 0.f;

        // prefetch tile 0 into regs
        short8 kst = *(const short8*)(kbase + (size_t)kkey * NKV + kdc * 8);
        short8 vst = *(const short8*)(vbase + (size_t)vdv * TT + vtc * 8);

        for (int t = 0; t < ntiles; t++) {
            int kb0 = t * 32;
            __syncthreads();   // previous tile's LDS readers done
            *(short8*)(Ks + kkey * 136 + kdc * 8) = kst;
            *(short8*)(Vs + vdv * 40 + vtc * 8) = vst;
            __syncthreads();
            if (t + 1 < ntiles) {   // prefetch next tile (overlaps compute below)
                int kn = kb0 + 32;
                kst = *(const short8*)(kbase + (size_t)(kn + kkey) * NKV + kdc * 8);
                vst = *(const short8*)(vbase + (size_t)vdv * TT + kn + vtc * 8);
            }
            // ---- S^T = K * Q^T : C rows = keys (quad*4+r), cols = qrows (l15) ----
            floatx4 s[2];
            s[0] = floatx4{0.f,0.f,0.f,0.f};
            s[1] = floatx4{0.f,0.f,0.f,0.f};
            __builtin_amdgcn_s_setprio(1);
#pragma unroll
            for (int ks = 0; ks < 4; ks++) {
                short8 kf0 = *(const short8*)(Ks + l15 * 136 + ks * 32 + quad * 8);
                short8 kf1 = *(const short8*)(Ks + (16 + l15) * 136 + ks * 32 + quad * 8);
                s[0] = __builtin_amdgcn_mfma_f32_16x16x32_bf16(kf0, qf[ks], s[0], 0, 0, 0);
                s[1] = __builtin_amdgcn_mfma_f32_16x16x32_bf16(kf1, qf[ks], s[1], 0, 0, 0);
            }
            __builtin_amdgcn_s_setprio(0);
            bool maskT = (t == ntiles - 1);   // only the diagonal tile needs masking
            int qrow = q0 + sub * 16 + l15;
            float p[8];
#pragma unroll
            for (int krt = 0; krt < 2; krt++)
#pragma unroll
                for (int r = 0; r < 4; r++) {
                    float v = s[krt][r] * scale2;
                    if (maskT && (kb0 + krt * 16 + quad * 4 + r > qrow)) v = -INFINITY;
                    p[krt * 4 + r] = v;
                }
            float mx = p[0];
#pragma unroll
            for (int j = 1; j < 8; j++) mx = fmaxf(mx, p[j]);
            mx = fmaxf(mx, __shfl_xor(mx, 16));
            mx = fmaxf(mx, __shfl_xor(mx, 32));
            // T13 defer-max: wave-uniform skip of the rescale pass
            bool noresc = (bool)__all(mx <= m_ + 8.0f);
            float mnew = noresc ? m_ : fmaxf(m_, mx);
            float e[8], sum = 0.f;
#pragma unroll
            for (int j = 0; j < 8; j++) { e[j] = exp2f(p[j] - mnew); sum += e[j]; }
            sum += __shfl_xor(sum, 16);
            sum += __shfl_xor(sum, 32);
            if (noresc) {
                l_ += sum;
            } else {
                float al = exp2f(m_ - mnew);
                l_ = l_ * al + sum;
                m_ = mnew;
                // broadcast alpha from lane l15=quad*4+r for O (row-indexed) rescale
                float ar[4];
#pragma unroll
                for (int r = 0; r < 4; r++) ar[r] = __shfl(al, quad * 4 + r);
#pragma unroll
                for (int vt = 0; vt < 8; vt++)
#pragma unroll
                    for (int r = 0; r < 4; r++) O[vt][r] *= ar[r];
            }
            // pack P^T -> LDS as P[qrow][key] (bf16, round-to-nearest)
            bshort4 pw0, pw1;
#pragma unroll
            for (int r = 0; r < 4; r++) {
                pw0[r] = (short)((__float_as_uint(e[r]) + 0x8000u) >> 16);
                pw1[r] = (short)((__float_as_uint(e[4 + r]) + 0x8000u) >> 16);
            }
            *(bshort4*)(P + l15 * 40 + quad * 4) = pw0;
            *(bshort4*)(P + l15 * 40 + 16 + quad * 4) = pw1;
            // ---- O += P * V^T : A = P (m=qrow), B = V^T (n=dv) ----
            short8 pf = *(const short8*)(P + l15 * 40 + quad * 8);
            __builtin_amdgcn_s_setprio(1);
#pragma unroll
            for (int vt = 0; vt < 8; vt++) {
                short8 vf = *(const short8*)(Vs + (vt * 16 + l15) * 40 + quad * 8);
                O[vt] = __builtin_amdgcn_mfma_f32_16x16x32_bf16(pf, vf, O[vt], 0, 0, 0);
            }
            __builtin_amdgcn_s_setprio(0);
        }
        // epilogue: O C-layout row = qrow (quad*4+r), col = dv (vt*16+l15)
        float lr[4];
#pragma unroll
        for (int r = 0; r < 4; r++) lr[r] = 1.0f / __shfl(l_, quad * 4 + r);
#pragma unroll
        for (int r = 0; r < 4; r++) {
            size_t row = (size_t)(b * TT + q0 + sub * 16 + quad * 4 + r);
#pragma unroll
            for (int vt = 0; vt < 8; vt++)
                ob[row * NQ + hq * DK + vt * 16 + l15] = f2bf(O[vt][r] * lr[r]);
        }
    }
}

extern "C" void kernel_launch(void* const* d_in, const int* in_sizes, int n_in,
                              void* d_out, int out_size, void* d_ws, size_t ws_size,
                              hipStream_t stream)
{
    const float* q  = (const float*)d_in[0];
    const float* k  = (const float*)d_in[1];
    const float* v  = (const float*)d_in[2];
    const float* wq = (const float*)d_in[3];
    const float* wk = (const float*)d_in[4];
    const float* wv = (const float*)d_in[5];
    const float* wo = (const float*)d_in[6];
    float* out   = (float*)d_out;                       // [2,2048,4096]
    float* cache = out + (size_t)MM * DD;               // [2,2048,8,256]

    char* ws = (char*)d_ws;
    float* cosT = (float*)ws;
    float* sinT = cosT + TT * 64;
    size_t off = 1u << 20;  // 1 MB
    const size_t SZ32 = (size_t)MM * DD * 2;   // 32 MB (bf16 4096x4096)
    const size_t SZ8  = (size_t)MM * NKV * 2;  // 8 MB  (bf16 4096x1024)
    uint16_t* wqT = (uint16_t*)(ws + off); off += SZ32;   // 4096x4096
    uint16_t* wkT = (uint16_t*)(ws + off); off += SZ8;    // 1024x4096
    uint16_t* wvT = (uint16_t*)(ws + off); off += SZ8;    // 1024x4096
    uint16_t* qb  = (uint16_t*)(ws + off); off += SZ32;
    uint16_t* kb  = (uint16_t*)(ws + off); off += SZ32;
    uint16_t* vb  = (uint16_t*)(ws + off); off += SZ32;
    uint16_t* khB = (uint16_t*)(ws + off); off += SZ8;
    uint16_t* vhB = (uint16_t*)(ws + off); off += SZ8;
    // aliases (stream-ordered reuse):
    uint16_t* vTr = wvT;  // after KV GEMM done with wvT
    uint16_t* qhB = vb;   // after KV GEMM done with vb
    uint16_t* woT = kb;   // after KV GEMM done with kb
    uint16_t* obf = qb;   // after Q GEMM done with qb

    // 1. RoPE tables
    rope_tables_k<<<TT, 64, 0, stream>>>(cosT, sinT);
    // 2. weight convert/transpose (wq, wk permuted for RoPE-pair locality; wv plain)
    wconv_k<true><<<dim3(NQ / 32, DD / 32), dim3(32, 8), 0, stream>>>(wq, wqT, DD, NQ);
    wconv_k<true><<<dim3(NKV / 32, DD / 32), dim3(32, 8), 0, stream>>>(wk, wkT, DD, NKV);
    wconv_k<false><<<dim3(NKV / 32, DD / 32), dim3(32, 8), 0, stream>>>(wv, wvT, DD, NKV);
    // 3. activation converts (fused q,k,v)
    int n4 = MM * DD / 4;
    aconv3_k<<<dim3((n4 + 255) / 256, 3), 256, 0, stream>>>(
        (const float4*)q, (const float4*)k, (const float4*)v,
        (uint2*)qb, (uint2*)kb, (uint2*)vb, n4);
    // 4. fused K+V GEMM (256^2; z=0: V bf16+cache, z=1: K rope+cache)
    gemm256_kv_k<<<dim3(NKV / 256, MM / 256, 2), 512, 0, stream>>>(
        kb, vb, wkT, wvT, khB, vhB, cache, cosT, sinT);
    // 5. Q GEMM (256^2; RoPE; writes qh bf16 into vb's space)
    gemm256_k<1><<<dim3(NQ / 256, MM / 256), 512, 0, stream>>>(qb, wqT, MM, NQ, DD, qhB, nullptr, cosT, sinT);
    // 6. wo convert (into kb's space)
    wconv_k<false><<<dim3(DD / 32, DD / 32), dim3(32, 8), 0, stream>>>(wo, woT, DD, DD);
    // 7. V transpose (into wvT's space)
    vtrans_k<<<dim3(TT / 32, DK / 32, BB * HKV), dim3(32, 8), 0, stream>>>(vhB, vTr);
    // 8. attention (into qb's space): grid = (qtile pairs, kv heads, batch), 512 thr
    attn_k<<<dim3(32, HKV, BB), 512, 0, stream>>>(qhB, khB, vTr, obf);
    // 9. output projection (256^2) -> fp32 out
    gemm256_k<4><<<dim3(DD / 256, MM / 256), 512, 0, stream>>>(obf, woT, MM, DD, DD, nullptr, out, cosT, sinT);
}

// Round 5
// 878.045 us; speedup vs baseline: 1.4242x; 1.0112x over previous
//
#include <hip/hip_runtime.h>
#include <hip/hip_bf16.h>
#include <cstdint>
#include <math.h>

// Problem dims (fixed)
#define BB 2
#define TT 2048
#define DD 4096
#define HQ 32
#define HKV 8
#define DK 128
#define MM (BB*TT)          // 4096 rows
#define NQ (HQ*DK)          // 4096
#define NKV (HKV*DK)        // 1024

typedef __attribute__((ext_vector_type(8))) short short8;
typedef __attribute__((ext_vector_type(4))) short bshort4;
typedef __attribute__((ext_vector_type(4))) float floatx4;

typedef unsigned int u32;
typedef __attribute__((address_space(1))) const u32 gas_u32;
typedef __attribute__((address_space(3))) u32 las_u32;

// async global->LDS, 16B per lane. LDS dest must be wave-uniform base + lane*16.
__device__ __forceinline__ void gl_lds16(const uint16_t* g, uint16_t* l) {
    __builtin_amdgcn_global_load_lds((gas_u32*)g, (las_u32*)l, 16, 0, 0);
}

__device__ inline uint16_t f2bf(float f) {
    uint32_t u = __float_as_uint(f);
    uint32_t r = (u + 0x7fffu + ((u >> 16) & 1u)) >> 16;
    return (uint16_t)r;
}

#define ASM_VMCNT8 asm volatile("s_waitcnt vmcnt(8)" ::: "memory")
#define ASM_VMCNT0 asm volatile("s_waitcnt vmcnt(0)" ::: "memory")
#define ASM_LGKM0  asm volatile("s_waitcnt lgkmcnt(0)" ::: "memory")
#define RAW_BAR    __builtin_amdgcn_s_barrier()
#define SCHED_B    __builtin_amdgcn_sched_barrier(0)

// bijective XCD swizzle for nwg%8==0 grids
__device__ __forceinline__ void swz_xy(int gx, int nwg, int& bx, int& by) {
    int idx = by * gx + bx;
    int cpx = nwg >> 3;
    idx = (idx & 7) * cpx + (idx >> 3);
    bx = idx % gx;
    by = idx / gx;
}

// ---------------- RoPE tables: cos/sin [2048][64] ----------------
__global__ void rope_tables_k(float* __restrict__ cosT, float* __restrict__ sinT) {
    int t = blockIdx.x;        // 0..2047
    int d = threadIdx.x;       // 0..63
    float theta = expf(-(float)d * (9.210340371976184f / 64.0f));
    float arg = (float)t * theta;
    float s, c;
    sincosf(arg, &s, &c);
    cosT[t * 64 + d] = c;
    sinT[t * 64 + d] = s;
}

// ------------- transpose-convert weights: W (K x N fp32) -> WT (N x K bf16) -------------
// PERM: swap bits 5<->6 of the output-column index (head-local). With the 256^2 GEMM's
// 64-col-per-wave layout this places both halves of each RoPE pair (d, d+64) in the
// same wave's accumulator (involution; epilogue applies the inverse when storing).
template <bool PERM>
__global__ void wconv_k(const float* __restrict__ W, uint16_t* __restrict__ WT, int K, int N) {
    __shared__ float tile[32][33];
    int n0 = blockIdx.x * 32, k0 = blockIdx.y * 32;
    int tx = threadIdx.x, ty = threadIdx.y;  // (32, 8)
#pragma unroll
    for (int i = 0; i < 4; i++) {
        int r = k0 + ty + i * 8;
        tile[ty + i * 8][tx] = W[(size_t)r * N + n0 + tx];
    }
    __syncthreads();
#pragma unroll
    for (int i = 0; i < 4; i++) {
        int r = n0 + ty + i * 8;
        int rp = r;
        if (PERM) rp = (r & ~96) | (((r >> 5) & 1) << 6) | (((r >> 6) & 1) << 5);
        WT[(size_t)rp * K + k0 + tx] = f2bf(tile[tx][ty + i * 8]);
    }
}

// ------------- activation convert fp32 -> bf16 (q,k,v in one launch) -------------
__global__ void aconv3_k(const float4* __restrict__ Xq, const float4* __restrict__ Xk,
                         const float4* __restrict__ Xv,
                         uint2* __restrict__ Yq, uint2* __restrict__ Yk, uint2* __restrict__ Yv,
                         int n4) {
    int i = blockIdx.x * blockDim.x + threadIdx.x;
    int w = blockIdx.y;
    const float4* X = (w == 0) ? Xq : (w == 1) ? Xk : Xv;
    uint2* Y = (w == 0) ? Yq : (w == 1) ? Yk : Yv;
    if (i < n4) {
        float4 v = X[i];
        uint2 o;
        o.x = (uint32_t)f2bf(v.x) | ((uint32_t)f2bf(v.y) << 16);
        o.y = (uint32_t)f2bf(v.z) | ((uint32_t)f2bf(v.w) << 16);
        Y[i] = o;
    }
}

// ================= 256x256 GEMM core, BK=64, 8 waves, double-buffered LDS =================
// T3+T4: loads for K-tile t+1 are ISSUED at the start of tile t (into the other buffer)
// and waited with counted vmcnt(8) at the start of tile t+1. Raw s_barrier (no vmcnt(0)
// drain) in the main loop. T2 swizzle: LDS 16B-chunk position c of row r holds global
// chunk c^(r&7); source pre-swizzled, read XORs (l15&7) -> conflict-free ds_read_b128.
// Compute region is left fence-free: B-fragments hoisted (read ONCE per K-tile, 8 reads)
// + per-qm A-fragments (2x8 reads) = 24 ds_read_b128/wave/tile; the compiler overlaps
// qm=1's reads under qm=0's MFMAs with its own counted lgkmcnt.
__device__ __forceinline__ void gemm256_core(
    const uint16_t* __restrict__ A, const uint16_t* __restrict__ Bm, int K,
    int m0, int n0, int tid, uint16_t* As2, uint16_t* Bs2, floatx4 acc[8][4])
{
    int lane = tid & 63;
    int l15 = lane & 15, quad = lane >> 4;
    int wave = tid >> 6;
    int wm = wave >> 2, wn = wave & 3;

#pragma unroll
    for (int a = 0; a < 8; a++)
#pragma unroll
        for (int b = 0; b < 4; b++) acc[a][b] = floatx4{0.f, 0.f, 0.f, 0.f};

    // staging: 512 thr; per matrix 256 rows x 8 chunks = 2048 chunks; 4 per thread.
    int srow = tid >> 3;                        // 0..63 (+i*64)
    int skc = (tid & 7) ^ (srow & 7);           // pre-swizzled source chunk
    const uint16_t* Ab = A + (size_t)(m0 + srow) * K + skc * 8;
    const uint16_t* Bb = Bm + (size_t)(n0 + srow) * K + skc * 8;
    uint16_t* AsD = As2 + tid * 8;              // + buf*16384 + i*4096
    uint16_t* BsD = Bs2 + tid * 8;
    int rsw = l15 & 7;                          // read-side XOR

    const int NT = K / 64;

    // prologue: stage tile 0 -> buf 0
#pragma unroll
    for (int i = 0; i < 4; i++) {
        gl_lds16(Ab + (size_t)(i * 64) * K, AsD + i * 4096);
        gl_lds16(Bb + (size_t)(i * 64) * K, BsD + i * 4096);
    }

    for (int t = 0; t < NT; ++t) {
        const uint16_t* bufA = As2 + (t & 1) * 16384;
        const uint16_t* bufB = Bs2 + (t & 1) * 16384;
        ASM_LGKM0;           // own ds_reads of previous tile retired
        SCHED_B;
        RAW_BAR;             // all waves done reading buf[(t+1)&1]'s old tile
        SCHED_B;
        if (t + 1 < NT) {    // issue next tile's loads into the other buffer
            int k0n = (t + 1) * 64;
            uint16_t* dA = As2 + ((t + 1) & 1) * 16384 + tid * 8;
            uint16_t* dB = Bs2 + ((t + 1) & 1) * 16384 + tid * 8;
#pragma unroll
            for (int i = 0; i < 4; i++) {
                gl_lds16(Ab + (size_t)(i * 64) * K + k0n, dA + i * 4096);
                gl_lds16(Bb + (size_t)(i * 64) * K + k0n, dB + i * 4096);
            }
            ASM_VMCNT8;      // tile t's 8 loads done; t+1's 8 stay in flight
        } else {
            ASM_VMCNT0;
        }
        SCHED_B;
        RAW_BAR;             // all waves' tile-t staging visible
        SCHED_B;

        // ---- compute tile t (no scheduling fences inside) ----
        // B-fragments once per K-tile: [qn][fn][ks], 8 ds_read_b128, 32 VGPR.
        short8 bfv[2][2][2];
#pragma unroll
        for (int qn = 0; qn < 2; qn++)
#pragma unroll
            for (int fn = 0; fn < 2; fn++)
#pragma unroll
                for (int ks = 0; ks < 2; ks++) {
                    int row = wn * 64 + qn * 32 + fn * 16 + l15;
                    bfv[qn][fn][ks] = *(const short8*)(bufB + row * 64 + ((((ks << 2) | quad) ^ rsw) << 3));
                }
#pragma unroll
        for (int qm = 0; qm < 2; qm++) {
            short8 af[4][2];
#pragma unroll
            for (int fm = 0; fm < 4; fm++)
#pragma unroll
                for (int ks = 0; ks < 2; ks++) {
                    int row = wm * 128 + qm * 64 + fm * 16 + l15;
                    af[fm][ks] = *(const short8*)(bufA + row * 64 + ((((ks << 2) | quad) ^ rsw) << 3));
                }
#pragma unroll
            for (int ks = 0; ks < 2; ks++)
#pragma unroll
                for (int fm = 0; fm < 4; fm++)
#pragma unroll
                    for (int qn = 0; qn < 2; qn++)
#pragma unroll
                        for (int fn = 0; fn < 2; fn++)
                            acc[qm * 4 + fm][qn * 2 + fn] = __builtin_amdgcn_mfma_f32_16x16x32_bf16(
                                af[fm][ks], bfv[qn][fn][ks], acc[qm * 4 + fm][qn * 2 + fn], 0, 0, 0);
        }
    }
}

// ------------- Q / O projection GEMM (256^2). EPI: 1=Q(rope->bf16, permuted W), 4=fp32 out -------------
template <int EPI>
__global__ __launch_bounds__(512, 2) void gemm256_k(
    const uint16_t* __restrict__ A, const uint16_t* __restrict__ Bm,
    int M, int N, int K,
    uint16_t* __restrict__ Obf, float* __restrict__ Ofp,
    const float* __restrict__ cosT, const float* __restrict__ sinT)
{
    __shared__ __attribute__((aligned(16))) uint16_t AB[4 * 16384];  // 128 KB
    int bx = blockIdx.x, by = blockIdx.y;
    swz_xy(gridDim.x, gridDim.x * gridDim.y, bx, by);
    int m0 = by * 256, n0 = bx * 256;
    int tid = threadIdx.x;
    int lane = tid & 63, wave = tid >> 6;
    int l15 = lane & 15, quad = lane >> 4;
    int wm = wave >> 2, wn = wave & 3;

    floatx4 acc[8][4];
    gemm256_core(A, Bm, K, m0, n0, tid, AB, AB + 2 * 16384, acc);

    if (EPI == 4) {
#pragma unroll
        for (int qm = 0; qm < 2; qm++)
#pragma unroll
            for (int fm = 0; fm < 4; fm++) {
                int rbase = m0 + wm * 128 + qm * 64 + fm * 16 + quad * 4;
#pragma unroll
                for (int qn = 0; qn < 2; qn++)
#pragma unroll
                    for (int fn = 0; fn < 2; fn++) {
                        int c = n0 + wn * 64 + qn * 32 + fn * 16 + l15;
#pragma unroll
                        for (int r = 0; r < 4; r++)
                            Ofp[(size_t)(rbase + r) * N + c] = acc[qm * 4 + fm][qn * 2 + fn][r];
                    }
            }
    } else {
        // Q RoPE epilogue. Wave's 64 phys cols (bit-5/6-swapped space): qn=0 holds x1
        // (logical d = j*32 + fn*16 + l15), qn=1 holds x2 (logical d+64).
        int c64 = n0 + wn * 64;
        int h = c64 >> 7;
        int j = (c64 >> 6) & 1;
#pragma unroll
        for (int qm = 0; qm < 2; qm++)
#pragma unroll
            for (int fm = 0; fm < 4; fm++) {
                int rbase = m0 + wm * 128 + qm * 64 + fm * 16 + quad * 4;
#pragma unroll
                for (int fn = 0; fn < 2; fn++) {
                    int d = j * 32 + fn * 16 + l15;
#pragma unroll
                    for (int r = 0; r < 4; r++) {
                        int row = rbase + r;
                        int t = row & (TT - 1);
                        float cs = cosT[t * 64 + d];
                        float sn = sinT[t * 64 + d];
                        float x1 = acc[qm * 4 + fm][fn][r];
                        float x2 = acc[qm * 4 + fm][2 + fn][r];
                        float o1 = x1 * cs - x2 * sn;
                        float o2 = x2 * cs + x1 * sn;
                        Obf[(size_t)row * N + h * 128 + d] = f2bf(o1);
                        Obf[(size_t)row * N + h * 128 + d + 64] = f2bf(o2);
                    }
                }
            }
    }
}

// ------------- fused K+V projection GEMM (256^2): blockIdx.z = 0 -> V, 1 -> K -------------
__global__ __launch_bounds__(512, 2) void gemm256_kv_k(
    const uint16_t* __restrict__ Akk, const uint16_t* __restrict__ Avv,
    const uint16_t* __restrict__ Wk, const uint16_t* __restrict__ Wv,
    uint16_t* __restrict__ khB, uint16_t* __restrict__ vhB, float* __restrict__ cache,
    const float* __restrict__ cosT, const float* __restrict__ sinT)
{
    __shared__ __attribute__((aligned(16))) uint16_t AB[4 * 16384];  // 128 KB
    bool isK = (blockIdx.z == 1);
    const uint16_t* A = isK ? Akk : Avv;
    const uint16_t* Bm = isK ? Wk : Wv;
    int bx = blockIdx.x, by = blockIdx.y;
    swz_xy(gridDim.x, gridDim.x * gridDim.y, bx, by);
    int m0 = by * 256, n0 = bx * 256;
    int tid = threadIdx.x;
    int lane = tid & 63, wave = tid >> 6;
    int l15 = lane & 15, quad = lane >> 4;
    int wm = wave >> 2, wn = wave & 3;

    floatx4 acc[8][4];
    gemm256_core(A, Bm, DD, m0, n0, tid, AB, AB + 2 * 16384, acc);

    if (!isK) {  // V: bf16 vh + fp32 cache[...,128+d]
#pragma unroll
        for (int qm = 0; qm < 2; qm++)
#pragma unroll
            for (int fm = 0; fm < 4; fm++) {
                int rbase = m0 + wm * 128 + qm * 64 + fm * 16 + quad * 4;
#pragma unroll
                for (int qn = 0; qn < 2; qn++)
#pragma unroll
                    for (int fn = 0; fn < 2; fn++) {
                        int c = n0 + wn * 64 + qn * 32 + fn * 16 + l15;
                        int h = c >> 7, cb = c & 127;
#pragma unroll
                        for (int r = 0; r < 4; r++) {
                            int row = rbase + r;
                            float v = acc[qm * 4 + fm][qn * 2 + fn][r];
                            vhB[(size_t)row * NKV + c] = f2bf(v);
                            cache[((size_t)row * 8 + h) * 256 + 128 + cb] = v;
                        }
                    }
            }
    } else {  // K with RoPE (permuted W): bf16 kh + fp32 cache, both logical layout
        int c64 = n0 + wn * 64;
        int h = c64 >> 7;
        int j = (c64 >> 6) & 1;
#pragma unroll
        for (int qm = 0; qm < 2; qm++)
#pragma unroll
            for (int fm = 0; fm < 4; fm++) {
                int rbase = m0 + wm * 128 + qm * 64 + fm * 16 + quad * 4;
#pragma unroll
                for (int fn = 0; fn < 2; fn++) {
                    int d = j * 32 + fn * 16 + l15;
#pragma unroll
                    for (int r = 0; r < 4; r++) {
                        int row = rbase + r;
                        int t = row & (TT - 1);
                        float cs = cosT[t * 64 + d];
                        float sn = sinT[t * 64 + d];
                        float x1 = acc[qm * 4 + fm][fn][r];
                        float x2 = acc[qm * 4 + fm][2 + fn][r];
                        float o1 = x1 * cs - x2 * sn;
                        float o2 = x2 * cs + x1 * sn;
                        khB[(size_t)row * NKV + h * 128 + d] = f2bf(o1);
                        khB[(size_t)row * NKV + h * 128 + d + 64] = f2bf(o2);
                        cache[((size_t)row * 8 + h) * 256 + d] = o1;
                        cache[((size_t)row * 8 + h) * 256 + d + 64] = o2;
                    }
                }
            }
    }
}

// ------------- transpose v_heads: vh[b*2048+t][h*128+d] -> vT[(b*8+h)*128+d][t] -------------
__global__ void vtrans_k(const uint16_t* __restrict__ vh, uint16_t* __restrict__ vT) {
    __shared__ uint16_t tile[32][33];
    int bh = blockIdx.z;           // b*8+h
    int t0 = blockIdx.x * 32;
    int d0 = blockIdx.y * 32;
    int b = bh >> 3, h = bh & 7;
    int tx = threadIdx.x, ty = threadIdx.y;
#pragma unroll
    for (int i = 0; i < 4; i++) {
        int t = t0 + ty + i * 8;
        tile[ty + i * 8][tx] = vh[(size_t)(b * TT + t) * NKV + h * DK + d0 + tx];
    }
    __syncthreads();
#pragma unroll
    for (int i = 0; i < 4; i++) {
        int d = d0 + ty + i * 8;
        vT[((size_t)bh * DK + d) * TT + t0 + tx] = tile[tx][ty + i * 8];
    }
}

// ------------- flash attention v2 — 8-wave / 16-qrow-per-wave -------------
__global__ __launch_bounds__(512, 4) void attn_k(
    const uint16_t* __restrict__ qh, const uint16_t* __restrict__ kh,
    const uint16_t* __restrict__ vT, uint16_t* __restrict__ ob)
{
    __shared__ __attribute__((aligned(16))) uint16_t Ks[32 * 136];   // [key][d], pad 8
    __shared__ __attribute__((aligned(16))) uint16_t Vs[128 * 40];   // [dv][key], pad 8
    __shared__ __attribute__((aligned(16))) uint16_t Ps[8 * 16 * 40];// per-wave P [qrow][key]

    int tid = threadIdx.x;
    int lane = tid & 63, wave = tid >> 6;     // 0..7
    int l15 = lane & 15, quad = lane >> 4;
    int sub = wave & 1, hg = wave >> 1;       // row-half, head-group
    int kvh = blockIdx.y;
    int b = blockIdx.z;
    int hq = hg * 8 + kvh;                    // Q heads of group = {kvh, kvh+8, +16, +24}
    uint16_t* P = Ps + wave * (16 * 40);

    const uint16_t* kbase = kh + (size_t)(b * TT) * NKV + kvh * DK;
    const uint16_t* vbase = vT + ((size_t)(b * 8 + kvh) * DK) * TT;
    const float scale2 = 0.08838834764831845f * 1.4426950408889634f;  // 1/sqrt(128) * log2(e)

    int kkey = tid >> 4, kdc = tid & 15;   // K staging: 32 keys x 16B chunks (512 thr)
    int vdv = tid >> 2, vtc = tid & 3;     // V staging: 128 dv x 4 chunks

    for (int half = 0; half < 2; half++) {
        int hh = half ? (63 - (int)blockIdx.x) : (int)blockIdx.x;
        int q0 = hh * 32;
        int ntiles = hh + 1;

        // Q B-frags (lane l15 = qrow, k = ks*32 + quad*8 + j)
        short8 qf[4];
        {
            const uint16_t* qr = qh + (size_t)(b * TT + q0 + sub * 16 + l15) * NQ + hq * DK;
#pragma unroll
            for (int ks = 0; ks < 4; ks++)
                qf[ks] = *(const short8*)(qr + ks * 32 + quad * 8);
        }

        floatx4 O[8];
#pragma unroll
        for (int vt = 0; vt < 8; vt++) O[vt] = floatx4{0.f, 0.f, 0.f, 0.f};
        float m_ = -INFINITY;
        float l_ = 0.f;

        // prefetch tile 0 into regs
        short8 kst = *(const short8*)(kbase + (size_t)kkey * NKV + kdc * 8);
        short8 vst = *(const short8*)(vbase + (size_t)vdv * TT + vtc * 8);

        for (int t = 0; t < ntiles; t++) {
            int kb0 = t * 32;
            __syncthreads();   // previous tile's LDS readers done
            *(short8*)(Ks + kkey * 136 + kdc * 8) = kst;
            *(short8*)(Vs + vdv * 40 + vtc * 8) = vst;
            __syncthreads();
            if (t + 1 < ntiles) {   // prefetch next tile (overlaps compute below)
                int kn = kb0 + 32;
                kst = *(const short8*)(kbase + (size_t)(kn + kkey) * NKV + kdc * 8);
                vst = *(const short8*)(vbase + (size_t)vdv * TT + kn + vtc * 8);
            }
            // ---- S^T = K * Q^T : C rows = keys (quad*4+r), cols = qrows (l15) ----
            floatx4 s[2];
            s[0] = floatx4{0.f,0.f,0.f,0.f};
            s[1] = floatx4{0.f,0.f,0.f,0.f};
            __builtin_amdgcn_s_setprio(1);
#pragma unroll
            for (int ks = 0; ks < 4; ks++) {
                short8 kf0 = *(const short8*)(Ks + l15 * 136 + ks * 32 + quad * 8);
                short8 kf1 = *(const short8*)(Ks + (16 + l15) * 136 + ks * 32 + quad * 8);
                s[0] = __builtin_amdgcn_mfma_f32_16x16x32_bf16(kf0, qf[ks], s[0], 0, 0, 0);
                s[1] = __builtin_amdgcn_mfma_f32_16x16x32_bf16(kf1, qf[ks], s[1], 0, 0, 0);
            }
            __builtin_amdgcn_s_setprio(0);
            bool maskT = (t == ntiles - 1);   // only the diagonal tile needs masking
            int qrow = q0 + sub * 16 + l15;
            float p[8];
#pragma unroll
            for (int krt = 0; krt < 2; krt++)
#pragma unroll
                for (int r = 0; r < 4; r++) {
                    float v = s[krt][r] * scale2;
                    if (maskT && (kb0 + krt * 16 + quad * 4 + r > qrow)) v = -INFINITY;
                    p[krt * 4 + r] = v;
                }
            float mx = p[0];
#pragma unroll
            for (int j = 1; j < 8; j++) mx = fmaxf(mx, p[j]);
            mx = fmaxf(mx, __shfl_xor(mx, 16));
            mx = fmaxf(mx, __shfl_xor(mx, 32));
            // T13 defer-max: wave-uniform skip of the rescale pass
            bool noresc = (bool)__all(mx <= m_ + 8.0f);
            float mnew = noresc ? m_ : fmaxf(m_, mx);
            float e[8], sum = 0.f;
#pragma unroll
            for (int j = 0; j < 8; j++) { e[j] = exp2f(p[j] - mnew); sum += e[j]; }
            sum += __shfl_xor(sum, 16);
            sum += __shfl_xor(sum, 32);
            if (noresc) {
                l_ += sum;
            } else {
                float al = exp2f(m_ - mnew);
                l_ = l_ * al + sum;
                m_ = mnew;
                // broadcast alpha from lane l15=quad*4+r for O (row-indexed) rescale
                float ar[4];
#pragma unroll
                for (int r = 0; r < 4; r++) ar[r] = __shfl(al, quad * 4 + r);
#pragma unroll
                for (int vt = 0; vt < 8; vt++)
#pragma unroll
                    for (int r = 0; r < 4; r++) O[vt][r] *= ar[r];
            }
            // pack P^T -> LDS as P[qrow][key] (bf16, round-to-nearest)
            bshort4 pw0, pw1;
#pragma unroll
            for (int r = 0; r < 4; r++) {
                pw0[r] = (short)((__float_as_uint(e[r]) + 0x8000u) >> 16);
                pw1[r] = (short)((__float_as_uint(e[4 + r]) + 0x8000u) >> 16);
            }
            *(bshort4*)(P + l15 * 40 + quad * 4) = pw0;
            *(bshort4*)(P + l15 * 40 + 16 + quad * 4) = pw1;
            // ---- O += P * V^T : A = P (m=qrow), B = V^T (n=dv) ----
            short8 pf = *(const short8*)(P + l15 * 40 + quad * 8);
            __builtin_amdgcn_s_setprio(1);
#pragma unroll
            for (int vt = 0; vt < 8; vt++) {
                short8 vf = *(const short8*)(Vs + (vt * 16 + l15) * 40 + quad * 8);
                O[vt] = __builtin_amdgcn_mfma_f32_16x16x32_bf16(pf, vf, O[vt], 0, 0, 0);
            }
            __builtin_amdgcn_s_setprio(0);
        }
        // epilogue: O C-layout row = qrow (quad*4+r), col = dv (vt*16+l15)
        float lr[4];
#pragma unroll
        for (int r = 0; r < 4; r++) lr[r] = 1.0f / __shfl(l_, quad * 4 + r);
#pragma unroll
        for (int r = 0; r < 4; r++) {
            size_t row = (size_t)(b * TT + q0 + sub * 16 + quad * 4 + r);
#pragma unroll
            for (int vt = 0; vt < 8; vt++)
                ob[row * NQ + hq * DK + vt * 16 + l15] = f2bf(O[vt][r] * lr[r]);
        }
    }
}

extern "C" void kernel_launch(void* const* d_in, const int* in_sizes, int n_in,
                              void* d_out, int out_size, void* d_ws, size_t ws_size,
                              hipStream_t stream)
{
    const float* q  = (const float*)d_in[0];
    const float* k  = (const float*)d_in[1];
    const float* v  = (const float*)d_in[2];
    const float* wq = (const float*)d_in[3];
    const float* wk = (const float*)d_in[4];
    const float* wv = (const float*)d_in[5];
    const float* wo = (const float*)d_in[6];
    float* out   = (float*)d_out;                       // [2,2048,4096]
    float* cache = out + (size_t)MM * DD;               // [2,2048,8,256]

    char* ws = (char*)d_ws;
    float* cosT = (float*)ws;
    float* sinT = cosT + TT * 64;
    size_t off = 1u << 20;  // 1 MB
    const size_t SZ32 = (size_t)MM * DD * 2;   // 32 MB (bf16 4096x4096)
    const size_t SZ8  = (size_t)MM * NKV * 2;  // 8 MB  (bf16 4096x1024)
    uint16_t* wqT = (uint16_t*)(ws + off); off += SZ32;   // 4096x4096
    uint16_t* wkT = (uint16_t*)(ws + off); off += SZ8;    // 1024x4096
    uint16_t* wvT = (uint16_t*)(ws + off); off += SZ8;    // 1024x4096
    uint16_t* qb  = (uint16_t*)(ws + off); off += SZ32;
    uint16_t* kb  = (uint16_t*)(ws + off); off += SZ32;
    uint16_t* vb  = (uint16_t*)(ws + off); off += SZ32;
    uint16_t* khB = (uint16_t*)(ws + off); off += SZ8;
    uint16_t* vhB = (uint16_t*)(ws + off); off += SZ8;
    // aliases (stream-ordered reuse):
    uint16_t* vTr = wvT;  // after KV GEMM done with wvT
    uint16_t* qhB = vb;   // after KV GEMM done with vb
    uint16_t* woT = kb;   // after KV GEMM done with kb
    uint16_t* obf = qb;   // after Q GEMM done with qb

    // 1. RoPE tables
    rope_tables_k<<<TT, 64, 0, stream>>>(cosT, sinT);
    // 2. weight convert/transpose (wq, wk permuted for RoPE-pair locality; wv plain)
    wconv_k<true><<<dim3(NQ / 32, DD / 32), dim3(32, 8), 0, stream>>>(wq, wqT, DD, NQ);
    wconv_k<true><<<dim3(NKV / 32, DD / 32), dim3(32, 8), 0, stream>>>(wk, wkT, DD, NKV);
    wconv_k<false><<<dim3(NKV / 32, DD / 32), dim3(32, 8), 0, stream>>>(wv, wvT, DD, NKV);
    // 3. activation converts (fused q,k,v)
    int n4 = MM * DD / 4;
    aconv3_k<<<dim3((n4 + 255) / 256, 3), 256, 0, stream>>>(
        (const float4*)q, (const float4*)k, (const float4*)v,
        (uint2*)qb, (uint2*)kb, (uint2*)vb, n4);
    // 4. fused K+V GEMM (256^2; z=0: V bf16+cache, z=1: K rope+cache)
    gemm256_kv_k<<<dim3(NKV / 256, MM / 256, 2), 512, 0, stream>>>(
        kb, vb, wkT, wvT, khB, vhB, cache, cosT, sinT);
    // 5. Q GEMM (256^2; RoPE; writes qh bf16 into vb's space)
    gemm256_k<1><<<dim3(NQ / 256, MM / 256), 512, 0, stream>>>(qb, wqT, MM, NQ, DD, qhB, nullptr, cosT, sinT);
    // 6. wo convert (into kb's space)
    wconv_k<false><<<dim3(DD / 32, DD / 32), dim3(32, 8), 0, stream>>>(wo, woT, DD, DD);
    // 7. V transpose (into wvT's space)
    vtrans_k<<<dim3(TT / 32, DK / 32, BB * HKV), dim3(32, 8), 0, stream>>>(vhB, vTr);
    // 8. attention (into qb's space): grid = (qtile pairs, kv heads, batch), 512 thr
    attn_k<<<dim3(32, HKV, BB), 512, 0, stream>>>(qhB, khB, vTr, obf);
    // 9. output projection (256^2) -> fp32 out
    gemm256_k<4><<<dim3(DD / 256, MM / 256), 512, 0, stream>>>(obf, woT, MM, DD, DD, nullptr, out, cosT, sinT);
}